// Round 14
// baseline (404.342 us; speedup 1.0000x reference)
//
#include <hip/hip_runtime.h>
#include <hip/hip_bf16.h>

typedef float f32x4 __attribute__((ext_vector_type(4)));
typedef __bf16 bf16x8 __attribute__((ext_vector_type(8)));
typedef unsigned short u16x8 __attribute__((ext_vector_type(8)));

// ---- constants: B=4, S=1024, dim=2048, H=16, D=128, T=1024, KV=2048, M=4096
#define DIMK 2048
#define QSCALE ((float)(0.08838834764831845 * 1.4426950408889634))  // 1/sqrt(128)*log2(e)

__device__ __forceinline__ unsigned short f2bf(float f) {
    union { float f; unsigned int u; } v; v.f = f;
    unsigned int r = v.u + 0x7fffu + ((v.u >> 16) & 1u);
    return (unsigned short)(r >> 16);
}
__device__ __forceinline__ float bf2f(unsigned short u) {
    union { unsigned int i; float f; } v; v.i = ((unsigned int)u) << 16; return v.f;
}

// async global->LDS 16B copy. LDS dest is wave-uniform base + lane*16.
__device__ __forceinline__ void lds_load16(void* lds, const void* gsrc) {
    __builtin_amdgcn_global_load_lds(
        (const __attribute__((address_space(1))) unsigned int*)gsrc,
        (__attribute__((address_space(3))) unsigned int*)lds,
        16, 0, 0);
}

// V permutation for PV A/B fragment layout: kv within 64-tile -> p slot.
// kv = kk*32 + a*16 + gv*4 + j  ->  p = kk*32 + gv*8 + a*4 + j  (j preserved)
__device__ __forceinline__ int vperm4(int kv4) {   // kv4 aligned to 4
    return ((kv4 >> 5) << 5) + (((kv4 >> 2) & 3) << 3) + (((kv4 >> 4) & 1) << 2);
}

// ================= fused prep kernel =================
// blocks 0..24575     : conv (x + 4 weights) -> bf16
// blocks 24576..32767 : k_dual (k_cache -> kout fp32 + Kbf bf16)
// blocks 32768..33791 : v_dual (v_cache -> vout fp32 + Vtp baked-LDS-image bf16)
// Vtp layout: [bh][tile t=kv/64][d*64 + (vperm(kv&63) ^ ((d&7)<<3))]  (16KB per tile)
__global__ __launch_bounds__(256) void prep_all(
    const float* __restrict__ x,  const float* __restrict__ Wq,
    const float* __restrict__ Wk, const float* __restrict__ Wv,
    const float* __restrict__ Wo,
    const float* __restrict__ kc, const float* __restrict__ vc,
    unsigned short* __restrict__ xbf, unsigned short* __restrict__ Wqb,
    unsigned short* __restrict__ Wkb, unsigned short* __restrict__ Wvb,
    unsigned short* __restrict__ Wob,
    float* __restrict__ kout, unsigned short* __restrict__ Kbf,
    float* __restrict__ vout, unsigned short* __restrict__ Vtp)
{
    const int bid = blockIdx.x;
    const int tid = threadIdx.x;

    if (bid < 24576) {
        int i = bid * 256 + tid;
        const float* src; unsigned short* dst; size_t off;
        if (i < 2097152) { src = x; dst = xbf; off = i; }
        else {
            int j = (i - 2097152) >> 20;
            off = (size_t)((i - 2097152) & 1048575);
            src = j == 0 ? Wq : j == 1 ? Wk : j == 2 ? Wv : Wo;
            dst = j == 0 ? Wqb : j == 1 ? Wkb : j == 2 ? Wvb : Wob;
        }
        f32x4 v = *(const f32x4*)(src + off * 4);
        ushort4 pk = { f2bf(v[0]), f2bf(v[1]), f2bf(v[2]), f2bf(v[3]) };
        *(ushort4*)(dst + off * 4) = pk;
    } else if (bid < 32768) {
        size_t i4 = (size_t)(bid - 24576) * 256 + tid;
        size_t e = i4 * 4;
        size_t bh = e >> 17, rem = e & 131071;
        f32x4 v = *(const f32x4*)(kc + e);
        size_t dsto = (bh << 18) + rem;
        *(f32x4*)(kout + dsto) = v;
        ushort4 pk = { f2bf(v[0]), f2bf(v[1]), f2bf(v[2]), f2bf(v[3]) };
        *(ushort4*)(Kbf + dsto) = pk;
    } else {
        __shared__ unsigned short T[128 * 72];
        const int o = bid - 32768;          // 0..1023
        const int t = o & 15;               // tile (cache rows 0..1023 -> tiles 0..15)
        const int kv0 = t * 64;
        const int bh = o >> 4;
        const float* src = vc + ((size_t)bh << 17) + (size_t)kv0 * 128;
        float* vdst = vout + ((size_t)bh << 18) + (size_t)kv0 * 128;
        #pragma unroll
        for (int r = 0; r < 8; ++r) {
            int e4 = r * 256 + tid;
            int kv = e4 >> 5, d0 = (e4 & 31) << 2;
            f32x4 v = *(const f32x4*)(src + kv * 128 + d0);
            *(f32x4*)(vdst + kv * 128 + d0) = v;
            #pragma unroll
            for (int i = 0; i < 4; ++i) T[(d0 + i) * 72 + kv] = f2bf(v[i]);
        }
        __syncthreads();
        unsigned short* tile = Vtp + ((size_t)bh * 32 + t) * 8192;
        #pragma unroll
        for (int r = 0; r < 8; ++r) {
            int e = r * 256 + tid;
            int d = e >> 4, k4 = (e & 15) << 2;
            ushort4 pk = { T[d * 72 + k4], T[d * 72 + k4 + 1], T[d * 72 + k4 + 2], T[d * 72 + k4 + 3] };
            const int idx = d * 64 + (vperm4(k4) ^ ((d & 7) << 3));
            *(ushort4*)(tile + idx) = pk;
        }
    }
}

// ================= GEMM core: BK=64, XOR-swizzled, double-buffered =================
// 128x128 tile, 4 waves (2x2), BK=64. LDS 2 x (16+16) KB = 64 KB.
// Issue next K-tile's DMA FIRST, compute current, ONE barrier per tile (attn9
// pattern): the pre-barrier vmcnt(0) drain then waits on loads that had the
// whole 32-MFMA compute phase to land -> fetch latency covered, not exposed.
// Swizzle (verified 0-conflict r13): pre-swizzled source chunk, matching read XOR.
__device__ __forceinline__ void gemm_core64db(
    const unsigned short* __restrict__ A16, const unsigned short* __restrict__ W16,
    int m0, int n0, int tid, int w, int g, int c, int wr, int wc,
    unsigned short* As, unsigned short* Bs, f32x4 (&acc)[4][4])
{
    const int srow = tid >> 3;                 // 0..31 (issue r adds 32)
    const int schk = (tid & 7) ^ (srow & 7);   // pre-swizzled source chunk
    const unsigned short* Asrc = A16 + (size_t)(m0 + srow) * DIMK + schk * 8;
    const unsigned short* Bsrc = W16 + (size_t)(n0 + srow) * DIMK + schk * 8;
    const int cswz = (c & 7) << 3;

    // prologue: stage K-tile 0 into buffer 0
    #pragma unroll
    for (int r = 0; r < 4; ++r) {
        lds_load16(As + r * 2048 + w * 512, Asrc + (size_t)r * 32 * DIMK);
        lds_load16(Bs + r * 2048 + w * 512, Bsrc + (size_t)r * 32 * DIMK);
    }
    __syncthreads();

    #pragma unroll 2
    for (int t = 0; t < 32; ++t) {
        const int cur = t & 1;
        const unsigned short* Ac = As + cur * 8192;
        const unsigned short* Bc = Bs + cur * 8192;

        // issue next tile's staging first (in flight under this tile's compute)
        if (t + 1 < 32) {
            unsigned short* An = As + (cur ^ 1) * 8192;
            unsigned short* Bn = Bs + (cur ^ 1) * 8192;
            const int k0 = (t + 1) * 64;
            #pragma unroll
            for (int r = 0; r < 4; ++r) {
                lds_load16(An + r * 2048 + w * 512, Asrc + (size_t)r * 32 * DIMK + k0);
                lds_load16(Bn + r * 2048 + w * 512, Bsrc + (size_t)r * 32 * DIMK + k0);
            }
        }

        #pragma unroll
        for (int kd = 0; kd < 2; ++kd) {
            const int ko = (kd * 32 + g * 8) ^ cswz;
            bf16x8 af[4], bfr[4];
            #pragma unroll
            for (int i = 0; i < 4; ++i)
                af[i] = *(const bf16x8*)(&Ac[(wr * 64 + i * 16 + c) * 64 + ko]);
            #pragma unroll
            for (int i = 0; i < 4; ++i)
                bfr[i] = *(const bf16x8*)(&Bc[(wc * 64 + i * 16 + c) * 64 + ko]);
            #pragma unroll
            for (int i = 0; i < 4; ++i)
                #pragma unroll
                for (int j = 0; j < 4; ++j)
                    acc[i][j] = __builtin_amdgcn_mfma_f32_16x16x32_bf16(af[i], bfr[j], acc[i][j], 0, 0, 0);
        }

        __syncthreads();   // drains vmcnt (t+1 landed) + all waves done with cur
    }
}

// Fused Q/K/V projection GEMM. 1536 linear blocks, XCD-chunked n-panels.
__global__ __launch_bounds__(256) void gemm_qkv(
    const unsigned short* __restrict__ xbf,
    const unsigned short* __restrict__ Wqb, const unsigned short* __restrict__ Wkb,
    const unsigned short* __restrict__ Wvb,
    const float* __restrict__ bq, const float* __restrict__ bk, const float* __restrict__ bv,
    unsigned short* __restrict__ Qbf,
    float* __restrict__ kout, unsigned short* __restrict__ Kbf,
    float* __restrict__ vout, unsigned short* __restrict__ Vtp)
{
    const int o = blockIdx.x;
    const int xcd = o & 7;
    const int k = o >> 3;
    const int mblk = k & 31;
    const int nloc = k >> 5;
    const int nblk = xcd * 6 + nloc;
    const int m0 = mblk * 128;
    const int n0g = nblk * 128;
    const int mi = n0g >> 11;
    const int n0 = n0g & 2047;

    const unsigned short* W16 = mi == 0 ? Wqb : (mi == 1 ? Wkb : Wvb);
    const float* bias = mi == 0 ? bq : (mi == 1 ? bk : bv);

    const int tid = threadIdx.x;
    const int lane = tid & 63;
    const int w = tid >> 6;
    const int g = lane >> 4;
    const int c = lane & 15;
    const int wr = w >> 1, wc = w & 1;

    __shared__ unsigned short As[2 * 128 * 64];
    __shared__ unsigned short Bs[2 * 128 * 64];

    f32x4 acc[4][4];
    #pragma unroll
    for (int i = 0; i < 4; ++i)
        #pragma unroll
        for (int j = 0; j < 4; ++j)
            acc[i][j] = f32x4{0.f, 0.f, 0.f, 0.f};

    gemm_core64db(xbf, W16, m0, n0, tid, w, g, c, wr, wc, As, Bs, acc);

    #pragma unroll
    for (int j = 0; j < 4; ++j) {
        const int n = n0 + wc * 64 + j * 16 + c;
        const float bn = bias[n];
        const int hh = n >> 7, d = n & 127;
        #pragma unroll
        for (int i = 0; i < 4; ++i) {
            float y4[4];
            #pragma unroll
            for (int tq = 0; tq < 4; ++tq) y4[tq] = acc[i][j][tq] + bn;
            const int mb = m0 + wr * 64 + i * 16 + g * 4;
            if (mi == 0) {
                #pragma unroll
                for (int tq = 0; tq < 4; ++tq) {
                    int m = mb + tq; int b = m >> 10, s = m & 1023;
                    Qbf[((((size_t)b * 16 + hh) << 10) + s) * 128 + d] = f2bf(y4[tq] * QSCALE);
                }
            } else if (mi == 1) {
                #pragma unroll
                for (int tq = 0; tq < 4; ++tq) {
                    int m = mb + tq; int b = m >> 10, s = m & 1023;
                    kout[(((size_t)b * 16 + hh) * 2048 + 1024 + s) * 128 + d] = y4[tq];
                    Kbf[(((size_t)b * 16 + hh) << 18) + (size_t)(1024 + s) * 128 + d] = f2bf(y4[tq]);
                }
            } else {
                #pragma unroll
                for (int tq = 0; tq < 4; ++tq) {
                    int m = mb + tq; int b = m >> 10, s = m & 1023;
                    vout[(((size_t)b * 16 + hh) * 2048 + 1024 + s) * 128 + d] = y4[tq];
                }
                // Vtp baked image: new rows kv=1024+s -> tile 16+(s>>6), slot vperm(s&63)
                int b = mb >> 10, s = mb & 1023;
                const int t = 16 + (s >> 6);
                const int idx = d * 64 + (vperm4(s & 63) ^ ((d & 7) << 3));
                ushort4 pk = { f2bf(y4[0]), f2bf(y4[1]), f2bf(y4[2]), f2bf(y4[3]) };
                *(ushort4*)(Vtp + ((size_t)(b * 16 + hh) * 32 + t) * 8192 + idx) = pk;
            }
        }
    }
}

// Output projection GEMM: 512 linear blocks, XCD-chunked.
__global__ __launch_bounds__(256) void gemm_wo(
    const unsigned short* __restrict__ ctx, const unsigned short* __restrict__ Wob,
    const float* __restrict__ bo, float* __restrict__ outp)
{
    const int o = blockIdx.x;
    const int xcd = o & 7;
    const int k = o >> 3;
    const int mblk = k & 31;
    const int nloc = k >> 5;
    const int nblk = xcd * 2 + nloc;
    const int m0 = mblk * 128;
    const int n0 = nblk * 128;

    const int tid = threadIdx.x;
    const int lane = tid & 63;
    const int w = tid >> 6;
    const int g = lane >> 4;
    const int c = lane & 15;
    const int wr = w >> 1, wc = w & 1;

    __shared__ unsigned short As[2 * 128 * 64];
    __shared__ unsigned short Bs[2 * 128 * 64];

    f32x4 acc[4][4];
    #pragma unroll
    for (int i = 0; i < 4; ++i)
        #pragma unroll
        for (int j = 0; j < 4; ++j)
            acc[i][j] = f32x4{0.f, 0.f, 0.f, 0.f};

    gemm_core64db(ctx, Wob, m0, n0, tid, w, g, c, wr, wc, As, Bs, acc);

    #pragma unroll
    for (int j = 0; j < 4; ++j) {
        const int n = n0 + wc * 64 + j * 16 + c;
        const float bn = bo[n];
        #pragma unroll
        for (int i = 0; i < 4; ++i) {
            const int mb = m0 + wr * 64 + i * 16 + g * 4;
            #pragma unroll
            for (int tq = 0; tq < 4; ++tq)
                outp[(size_t)(mb + tq) * 2048 + n] = acc[i][j][tq] + bn;
        }
    }
}

// ================= flash attention v9: 8 waves x 16 q-rows, all-DMA staging ==========
// (unchanged, known-good: ~110us, 16 waves/CU)
__global__ __launch_bounds__(512) void attn9(
    const unsigned short* __restrict__ Qbf,   // [B,H,1024,128] pre-scaled
    const unsigned short* __restrict__ Kbf,   // [B,H,2048,128]
    const unsigned short* __restrict__ Vtp,   // [B,H,32,8192] baked LDS images
    unsigned short* __restrict__ Pp,          // [2][64][1024][128] bf16 partials
    float* __restrict__ Mp,                   // [2][64][1024]
    float* __restrict__ Lp)                   // [2][64][1024]
{
    const int o = blockIdx.x;
    const int xcd = o & 7;
    const int kk0 = o >> 3;
    const int half = kk0 & 1;
    const int qt = 7 - ((kk0 >> 1) & 7);      // heavy-first
    const int bh = (kk0 >> 4) * 8 + xcd;

    const int tid = threadIdx.x;              // 0..511
    const int lane = tid & 63;
    const int w = tid >> 6;                   // 0..7
    const int g = lane >> 4;
    const int c = lane & 15;
    const int cswz = (c & 7) << 3;

    __shared__ unsigned short Ks[2][64 * 128];   // 32 KB
    __shared__ unsigned short Vs[2][64 * 128];   // 32 KB ([d][p] image)

    const unsigned short* Qb = Qbf + ((size_t)bh * 1024 + qt * 128) * 128;
    const unsigned short* Kb = Kbf + ((size_t)bh << 18);
    const unsigned short* Vtile = Vtp + (size_t)bh * 32 * 8192;

    bf16x8 aq[4];
    #pragma unroll
    for (int kd = 0; kd < 4; ++kd)
        aq[kd] = *(const bf16x8*)(Qb + (w * 16 + c) * 128 + kd * 32 + g * 8);

    f32x4 od[8];
    #pragma unroll
    for (int nf = 0; nf < 8; ++nf)
        od[nf] = f32x4{0.f, 0.f, 0.f, 0.f};
    float mrow = -1e30f, lrow = 0.f;

    const int krow = tid >> 4;
    const int kswz = (((tid & 15) << 4) ^ ((krow & 7) << 4)) >> 1;
    const unsigned short* Kl = Kb + (size_t)krow * 128 + kswz;

    const int cnt = 9 + qt;
    const int t0 = half * cnt;
    const int limw = 1024 + qt * 128 + w * 16;

    {
        const int kv0 = t0 * 64;
        lds_load16(&Ks[0][w * 512], Kl + (size_t)kv0 * 128);
        lds_load16(&Ks[0][4096 + w * 512], Kl + (size_t)(kv0 + 32) * 128);
        const unsigned short* Vsrc = Vtile + (size_t)t0 * 8192 + tid * 8;
        lds_load16(&Vs[0][w * 512], Vsrc);
        lds_load16(&Vs[0][4096 + w * 512], Vsrc + 4096);
        __syncthreads();
    }

    int cur = 0;
    for (int t = t0; t < t0 + cnt; ++t) {
        const int kv0 = t * 64;
        const bool next = (t + 1 < t0 + cnt);

        if (next) {
            const int kvn = kv0 + 64;
            lds_load16(&Ks[cur ^ 1][w * 512], Kl + (size_t)kvn * 128);
            lds_load16(&Ks[cur ^ 1][4096 + w * 512], Kl + (size_t)(kvn + 32) * 128);
            const unsigned short* Vsrc = Vtile + (size_t)(t + 1) * 8192 + tid * 8;
            lds_load16(&Vs[cur ^ 1][w * 512], Vsrc);
            lds_load16(&Vs[cur ^ 1][4096 + w * 512], Vsrc + 4096);
        }

        const unsigned short* Ksc = &Ks[cur][0];
        const unsigned short* Vsc = &Vs[cur][0];

        f32x4 sc[4];
        #pragma unroll
        for (int n = 0; n < 4; ++n)
            sc[n] = f32x4{0.f, 0.f, 0.f, 0.f};
        #pragma unroll
        for (int kd = 0; kd < 4; ++kd) {
            bf16x8 bk[4];
            #pragma unroll
            for (int n = 0; n < 4; ++n)
                bk[n] = *(const bf16x8*)(&Ksc[(n * 16 + c) * 128 + ((kd * 32 + g * 8) ^ cswz)]);
            #pragma unroll
            for (int n = 0; n < 4; ++n)
                sc[n] = __builtin_amdgcn_mfma_f32_16x16x32_bf16(bk[n], aq[kd], sc[n], 0, 0, 0);
        }

        const bool need_mask = (kv0 + 63 > limw);
        if (need_mask) {
            const int lim = limw + c;
            #pragma unroll
            for (int n = 0; n < 4; ++n)
                #pragma unroll
                for (int j = 0; j < 4; ++j)
                    if (kv0 + n * 16 + g * 4 + j > lim) sc[n][j] = -1e30f;
        }
        {
            float t4[4];
            #pragma unroll
            for (int n = 0; n < 4; ++n)
                t4[n] = fmaxf(fmaxf(sc[n][0], sc[n][1]), fmaxf(sc[n][2], sc[n][3]));
            float rmax = fmaxf(fmaxf(t4[0], t4[1]), fmaxf(t4[2], t4[3]));
            rmax = fmaxf(rmax, __shfl_xor(rmax, 16));
            rmax = fmaxf(rmax, __shfl_xor(rmax, 32));

            if (!__all(rmax <= mrow + 8.0f)) {
                const float mnew = fmaxf(mrow, rmax);
                const float fs = exp2f(mrow - mnew);
                mrow = mnew;
                lrow *= fs;
                #pragma unroll
                for (int j = 0; j < 4; ++j) {
                    const float fsj = __shfl(fs, (lane & 48) | (g * 4 + j));
                    #pragma unroll
                    for (int nf = 0; nf < 8; ++nf)
                        od[nf][j] *= fsj;
                }
            }
            const float mm = mrow;
            float s4[4];
            #pragma unroll
            for (int n = 0; n < 4; ++n) {
                #pragma unroll
                for (int j = 0; j < 4; ++j)
                    sc[n][j] = exp2f(sc[n][j] - mm);
                s4[n] = (sc[n][0] + sc[n][1]) + (sc[n][2] + sc[n][3]);
            }
            float rsum = (s4[0] + s4[1]) + (s4[2] + s4[3]);
            rsum += __shfl_xor(rsum, 16);
            rsum += __shfl_xor(rsum, 32);
            lrow += rsum;
        }

        bf16x8 pa[2];
        #pragma unroll
        for (int kk = 0; kk < 2; ++kk)
            #pragma unroll
            for (int e = 0; e < 8; ++e)
                pa[kk][e] = (__bf16)sc[2 * kk + (e >> 2)][e & 3];

        #pragma unroll
        for (int kk = 0; kk < 2; ++kk) {
            #pragma unroll
            for (int nf = 0; nf < 8; ++nf) {
                bf16x8 bv = *(const bf16x8*)(&Vsc[(nf * 16 + c) * 64 + ((kk * 32 + g * 8) ^ cswz)]);
                od[nf] = __builtin_amdgcn_mfma_f32_16x16x32_bf16(pa[kk], bv, od[nf], 0, 0, 0);
            }
        }

        __syncthreads();
        cur ^= 1;
    }

    const size_t pbase = ((size_t)(half * 64 + bh) * 1024 + qt * 128) * 128;
    const int mlbase = (half * 64 + bh) * 1024 + qt * 128;
    if (lane < 16) {
        Mp[mlbase + w * 16 + c] = mrow;
        Lp[mlbase + w * 16 + c] = lrow;
    }
    #pragma unroll
    for (int j = 0; j < 4; ++j) {
        const float lj = __shfl(lrow, (lane & 48) | (g * 4 + j));
        const float rl = 1.0f / lj;
        const int ql = w * 16 + g * 4 + j;
        #pragma unroll
        for (int nf = 0; nf < 8; ++nf)
            Pp[pbase + (size_t)ql * 128 + nf * 16 + c] = f2bf(od[nf][j] * rl);
    }
}

// merge the two KV-split partials -> ctx bf16
__global__ __launch_bounds__(256) void merge_ctx(
    const unsigned short* __restrict__ Pp, const float* __restrict__ Mp,
    const float* __restrict__ Lp, unsigned short* __restrict__ ctx)
{
    const int idx = blockIdx.x * 256 + threadIdx.x;
    const int r = idx >> 4;
    const int dc = (idx & 15) << 3;
    const float m0 = Mp[r], m1 = Mp[65536 + r];
    const float l0 = Lp[r], l1 = Lp[65536 + r];
    const float M = fmaxf(m0, m1);
    float w0 = l0 * exp2f(m0 - M);
    float w1 = l1 * exp2f(m1 - M);
    const float inv = 1.0f / (w0 + w1);
    w0 *= inv; w1 *= inv;
    u16x8 a = *(const u16x8*)(Pp + (size_t)r * 128 + dc);
    u16x8 bb = *(const u16x8*)(Pp + (size_t)8388608 + (size_t)r * 128 + dc);
    const int bh = r >> 10, q = r & 1023;
    unsigned short* dst = ctx + ((size_t)(bh >> 4) * 1024 + q) * 2048 + (bh & 15) * 128 + dc;
    u16x8 outv;
    #pragma unroll
    for (int e = 0; e < 8; ++e)
        outv[e] = f2bf(w0 * bf2f(a[e]) + w1 * bf2f(bb[e]));
    *(u16x8*)dst = outv;
}

// ================= small-ws fallback =================
__global__ __launch_bounds__(256) void copy_cache(
    const float* __restrict__ kc, const float* __restrict__ vc,
    float* __restrict__ kout, float* __restrict__ vout)
{
    size_t i4 = (size_t)blockIdx.x * 256 + threadIdx.x;
    const float* src = blockIdx.y ? vc : kc;
    float* dst = blockIdx.y ? vout : kout;
    size_t e = i4 * 4;
    size_t bh = e >> 17, rem = e & 131071;
    f32x4 v = *(const f32x4*)(src + e);
    *(f32x4*)(dst + (bh << 18) + rem) = v;
}

template<int MODE, bool ABF16>
__global__ __launch_bounds__(256) void gemm_bt(
    const void* __restrict__ Ag, const float* __restrict__ Wf,
    const float* __restrict__ bias, void* __restrict__ dst)
{
    const int tid = threadIdx.x;
    const int lane = tid & 63;
    const int w = tid >> 6;
    const int g = lane >> 4;
    const int c = lane & 15;
    const int wr = w >> 1, wc = w & 1;
    const int m0 = blockIdx.y * 128;
    const int n0 = blockIdx.x * 128;

    __shared__ unsigned short As[128 * 40];
    __shared__ unsigned short Bs[128 * 40];

    f32x4 acc[4][4];
    #pragma unroll
    for (int i = 0; i < 4; ++i)
        #pragma unroll
        for (int j = 0; j < 4; ++j)
            acc[i][j] = f32x4{0.f, 0.f, 0.f, 0.f};

    for (int k0 = 0; k0 < DIMK; k0 += 32) {
        __syncthreads();
        if constexpr (ABF16) {
            const unsigned short* A16 = (const unsigned short*)Ag;
            #pragma unroll
            for (int r = 0; r < 2; ++r) {
                int e8 = r * 256 + tid;
                int row = e8 >> 2, col = (e8 & 3) << 3;
                *(uint4*)(&As[row * 40 + col]) =
                    *(const uint4*)(A16 + (size_t)(m0 + row) * DIMK + k0 + col);
            }
        } else {
            const float* Af = (const float*)Ag;
            #pragma unroll
            for (int r = 0; r < 4; ++r) {
                int e4 = r * 256 + tid;
                int row = e4 >> 3, col = (e4 & 7) << 2;
                f32x4 v = *(const f32x4*)(Af + (size_t)(m0 + row) * DIMK + k0 + col);
                ushort4 pk = { f2bf(v[0]), f2bf(v[1]), f2bf(v[2]), f2bf(v[3]) };
                *(ushort4*)(&As[row * 40 + col]) = pk;
            }
        }
        {
            #pragma unroll
            for (int r = 0; r < 4; ++r) {
                int e4 = r * 256 + tid;
                int row = e4 >> 3, col = (e4 & 7) << 2;
                f32x4 v = *(const f32x4*)(Wf + (size_t)(n0 + row) * DIMK + k0 + col);
                ushort4 pk = { f2bf(v[0]), f2bf(v[1]), f2bf(v[2]), f2bf(v[3]) };
                *(ushort4*)(&Bs[row * 40 + col]) = pk;
            }
        }
        __syncthreads();

        bf16x8 af[4], bfr[4];
        #pragma unroll
        for (int i = 0; i < 4; ++i)
            af[i] = *(const bf16x8*)(&As[(wr * 64 + i * 16 + c) * 40 + g * 8]);
        #pragma unroll
        for (int i = 0; i < 4; ++i)
            bfr[i] = *(const bf16x8*)(&Bs[(wc * 64 + i * 16 + c) * 40 + g * 8]);
        #pragma unroll
        for (int i = 0; i < 4; ++i)
            #pragma unroll
            for (int j = 0; j < 4; ++j)
                acc[i][j] = __builtin_amdgcn_mfma_f32_16x16x32_bf16(af[i], bfr[j], acc[i][j], 0, 0, 0);
    }

    #pragma unroll
    for (int j = 0; j < 4; ++j) {
        const int n = n0 + wc * 64 + j * 16 + c;
        const float bn = bias[n];
        #pragma unroll
        for (int i = 0; i < 4; ++i) {
            float y4[4];
            #pragma unroll
            for (int tq = 0; tq < 4; ++tq) y4[tq] = acc[i][j][tq] + bn;
            const int mb = m0 + wr * 64 + i * 16 + g * 4;
            if constexpr (MODE == 0) {
                #pragma unroll
                for (int tq = 0; tq < 4; ++tq) {
                    int m = mb + tq; int b = m >> 10, s = m & 1023;
                    int hh = n >> 7, d = n & 127;
                    ((unsigned short*)dst)[((((size_t)b * 16 + hh) << 10) + s) * 128 + d] = f2bf(y4[tq] * QSCALE);
                }
            } else if constexpr (MODE == 1) {
                #pragma unroll
                for (int tq = 0; tq < 4; ++tq) {
                    int m = mb + tq; int b = m >> 10, s = m & 1023;
                    int hh = n >> 7, d = n & 127;
                    ((float*)dst)[(((size_t)b * 16 + hh) * 2048 + 1024 + s) * 128 + d] = y4[tq];
                }
            } else {
                #pragma unroll
                for (int tq = 0; tq < 4; ++tq)
                    ((float*)dst)[(size_t)(mb + tq) * 2048 + n] = y4[tq];
            }
        }
    }
}

__global__ __launch_bounds__(256) void attn_stage(
    const unsigned short* __restrict__ Qbf,
    const float* __restrict__ Kf, const float* __restrict__ Vf,
    unsigned short* __restrict__ ctx)
{
    const int qt = blockIdx.x;
    const int bh = blockIdx.y;
    const int b = bh >> 4, h = bh & 15;
    const int tid = threadIdx.x;
    const int lane = tid & 63;
    const int w = tid >> 6;
    const int g = lane >> 4;
    const int c = lane & 15;

    __shared__ unsigned short Ksl[64 * 136];
    __shared__ unsigned short Vtl[128 * 72];
    __shared__ unsigned short Ps[4 * 32 * 72];

    bf16x8 aq[2][4];
    const unsigned short* Qb = Qbf + ((size_t)bh * 1024 + qt * 128) * 128;
    #pragma unroll
    for (int m2 = 0; m2 < 2; ++m2)
        #pragma unroll
        for (int kk = 0; kk < 4; ++kk)
            aq[m2][kk] = *(const bf16x8*)(Qb + (w * 32 + m2 * 16 + c) * 128 + kk * 32 + g * 8);

    f32x4 od[2][8];
    #pragma unroll
    for (int m2 = 0; m2 < 2; ++m2)
        #pragma unroll
        for (int nf = 0; nf < 8; ++nf)
            od[m2][nf] = f32x4{0.f, 0.f, 0.f, 0.f};
    float mrow[2][4], lrow[2][4];
    #pragma unroll
    for (int m2 = 0; m2 < 2; ++m2)
        #pragma unroll
        for (int j = 0; j < 4; ++j) { mrow[m2][j] = -1e30f; lrow[m2][j] = 0.f; }

    const float* Kb = Kf + (size_t)bh * 2048 * 128;
    const float* Vb = Vf + (size_t)bh * 2048 * 128;
    const int ntiles = 18 + 2 * qt;

    for (int t = 0; t < ntiles; ++t) {
        __syncthreads();
        const float* Kt = Kb + (size_t)t * 64 * 128;
        #pragma unroll
        for (int r = 0; r < 8; ++r) {
            int e4 = r * 256 + tid;
            int kv = e4 >> 5, d0 = (e4 & 31) << 2;
            f32x4 v = *(const f32x4*)(Kt + kv * 128 + d0);
            ushort4 pk = { f2bf(v[0]), f2bf(v[1]), f2bf(v[2]), f2bf(v[3]) };
            *(ushort4*)(&Ksl[kv * 136 + d0]) = pk;
        }
        const float* Vg = Vb + (size_t)t * 64 * 128;
        #pragma unroll
        for (int r = 0; r < 8; ++r) {
            int e4 = tid * 8 + r;
            int kv = e4 >> 5, d0 = (e4 & 31) << 2;
            f32x4 v = *(const f32x4*)(Vg + kv * 128 + d0);
            #pragma unroll
            for (int i = 0; i < 4; ++i)
                Vtl[(d0 + i) * 72 + kv] = f2bf(v[i]);
        }
        __syncthreads();

        f32x4 sc[2][4];
        #pragma unroll
        for (int m2 = 0; m2 < 2; ++m2)
            #pragma unroll
            for (int n = 0; n < 4; ++n)
                sc[m2][n] = f32x4{0.f, 0.f, 0.f, 0.f};
        #pragma unroll
        for (int kk = 0; kk < 4; ++kk) {
            bf16x8 bk[4];
            #pragma unroll
            for (int n = 0; n < 4; ++n)
                bk[n] = *(const bf16x8*)(&Ksl[(n * 16 + c) * 136 + kk * 32 + g * 8]);
            #pragma unroll
            for (int m2 = 0; m2 < 2; ++m2)
                #pragma unroll
                for (int n = 0; n < 4; ++n)
                    sc[m2][n] = __builtin_amdgcn_mfma_f32_16x16x32_bf16(aq[m2][kk], bk[n], sc[m2][n], 0, 0, 0);
        }

        const int kvbase = t * 64;
        #pragma unroll
        for (int m2 = 0; m2 < 2; ++m2) {
            #pragma unroll
            for (int j = 0; j < 4; ++j) {
                const int qg = qt * 128 + w * 32 + m2 * 16 + g * 4 + j;
                const int lim = qg + 1024;
                float rmax = -1e30f;
                #pragma unroll
                for (int n = 0; n < 4; ++n) {
                    float s = sc[m2][n][j] * QSCALE;
                    if (kvbase + n * 16 + c > lim) s = -1e30f;
                    sc[m2][n][j] = s;
                    rmax = fmaxf(rmax, s);
                }
                #pragma unroll
                for (int off = 1; off < 16; off <<= 1)
                    rmax = fmaxf(rmax, __shfl_xor(rmax, off));
                float mold = mrow[m2][j];
                float mnew = fmaxf(mold, rmax);
                mrow[m2][j] = mnew;
                float fs = exp2f(mold - mnew);
                float rsum = 0.f;
                #pragma unroll
                for (int n = 0; n < 4; ++n) {
                    float p = exp2f(sc[m2][n][j] - mnew);
                    sc[m2][n][j] = p;
                    rsum += p;
                }
                #pragma unroll
                for (int off = 1; off < 16; off <<= 1)
                    rsum += __shfl_xor(rsum, off);
                lrow[m2][j] = lrow[m2][j] * fs + rsum;
                #pragma unroll
                for (int nf = 0; nf < 8; ++nf)
                    od[m2][nf][j] *= fs;
            }
        }

        unsigned short* Pw = &Ps[w * 32 * 72];
        #pragma unroll
        for (int m2 = 0; m2 < 2; ++m2)
            #pragma unroll
            for (int n = 0; n < 4; ++n)
                #pragma unroll
                for (int j = 0; j < 4; ++j)
                    Pw[(m2 * 16 + g * 4 + j) * 72 + n * 16 + c] = f2bf(sc[m2][n][j]);

        #pragma unroll
        for (int kk = 0; kk < 2; ++kk) {
            bf16x8 ap0 = *(const bf16x8*)(&Ps[(w * 32 + c) * 72 + kk * 32 + g * 8]);
            bf16x8 ap1 = *(const bf16x8*)(&Ps[(w * 32 + 16 + c) * 72 + kk * 32 + g * 8]);
            #pragma unroll
            for (int nf = 0; nf < 8; ++nf) {
                bf16x8 bv = *(const bf16x8*)(&Vtl[(nf * 16 + c) * 72 + kk * 32 + g * 8]);
                od[0][nf] = __builtin_amdgcn_mfma_f32_16x16x32_bf16(ap0, bv, od[0][nf], 0, 0, 0);
                od[1][nf] = __builtin_amdgcn_mfma_f32_16x16x32_bf16(ap1, bv, od[1][nf], 0, 0, 0);
            }
        }
    }

    #pragma unroll
    for (int m2 = 0; m2 < 2; ++m2) {
        #pragma unroll
        for (int j = 0; j < 4; ++j) {
            const int qg = qt * 128 + w * 32 + m2 * 16 + g * 4 + j;
            const float rl = 1.0f / lrow[m2][j];
            #pragma unroll
            for (int nf = 0; nf < 8; ++nf) {
                const int d = nf * 16 + c;
                ctx[((size_t)b * 1024 + qg) * 2048 + h * 128 + d] = f2bf(od[m2][nf][j] * rl);
            }
        }
    }
}

extern "C" void kernel_launch(void* const* d_in, const int* in_sizes, int n_in,
                              void* d_out, int out_size, void* d_ws, size_t ws_size,
                              hipStream_t stream) {
    const float* x  = (const float*)d_in[0];
    const float* kc = (const float*)d_in[1];
    const float* vc = (const float*)d_in[2];
    const float* Wq = (const float*)d_in[3];
    const float* bq = (const float*)d_in[4];
    const float* Wk = (const float*)d_in[5];
    const float* bk = (const float*)d_in[6];
    const float* Wv = (const float*)d_in[7];
    const float* bv = (const float*)d_in[8];
    const float* Wo = (const float*)d_in[9];
    const float* bo = (const float*)d_in[10];

    float* outp = (float*)d_out;
    float* kout = outp + (size_t)8388608;
    float* vout = outp + (size_t)25165824;

    unsigned short* Qbf = (unsigned short*)d_ws;          //  8,388,608
    unsigned short* ctx = Qbf + (size_t)8388608;          //  8,388,608
    unsigned short* Kbf = ctx + (size_t)8388608;          // 16,777,216
    unsigned short* Vtp = Kbf + (size_t)16777216;         // 16,777,216 (baked V images)
    unsigned short* xbf = Vtp + (size_t)16777216;         //  8,388,608
    unsigned short* Wqb = xbf + (size_t)8388608;
    unsigned short* Wkb = Wqb + (size_t)4194304;
    unsigned short* Wvb = Wkb + (size_t)4194304;
    unsigned short* Wob = Wvb + (size_t)4194304;
    unsigned short* Pp = xbf;                             // reuse xbf+Wqb+Wkb
    float* Mp = (float*)Wvb;
    float* Lp = Mp + (size_t)131072;

    const bool full = ws_size >= (size_t)150994944;

    if (full) {
        prep_all<<<33792, 256, 0, stream>>>(x, Wq, Wk, Wv, Wo, kc, vc,
                                            xbf, Wqb, Wkb, Wvb, Wob,
                                            kout, Kbf, vout, Vtp);
        gemm_qkv<<<1536, 256, 0, stream>>>(xbf, Wqb, Wkb, Wvb, bq, bk, bv,
                                           Qbf, kout, Kbf, vout, Vtp);
        attn9<<<1024, 512, 0, stream>>>(Qbf, Kbf, Vtp, Pp, Mp, Lp);
        merge_ctx<<<4096, 256, 0, stream>>>(Pp, Mp, Lp, ctx);
        gemm_wo<<<512, 256, 0, stream>>>(ctx, Wob, bo, outp);
    } else {
        copy_cache<<<dim3(8192, 2), 256, 0, stream>>>(kc, vc, kout, vout);
        gemm_bt<0, false><<<dim3(16, 32), 256, 0, stream>>>(x, Wq, bq, Qbf);
        gemm_bt<1, false><<<dim3(16, 32), 256, 0, stream>>>(x, Wk, bk, kout);
        gemm_bt<1, false><<<dim3(16, 32), 256, 0, stream>>>(x, Wv, bv, vout);
        attn_stage<<<dim3(8, 64), 256, 0, stream>>>(Qbf, kout, vout, ctx);
        gemm_bt<2, true><<<dim3(16, 32), 256, 0, stream>>>(ctx, Wo, bo, outp);
    }
}

// Round 15
// 376.826 us; speedup vs baseline: 1.0730x; 1.0730x over previous
//
#include <hip/hip_runtime.h>
#include <hip/hip_bf16.h>

typedef float f32x4 __attribute__((ext_vector_type(4)));
typedef __bf16 bf16x8 __attribute__((ext_vector_type(8)));
typedef unsigned short u16x8 __attribute__((ext_vector_type(8)));

// ---- constants: B=4, S=1024, dim=2048, H=16, D=128, T=1024, KV=2048, M=4096
#define DIMK 2048
#define QSCALE ((float)(0.08838834764831845 * 1.4426950408889634))  // 1/sqrt(128)*log2(e)

__device__ __forceinline__ unsigned short f2bf(float f) {
    union { float f; unsigned int u; } v; v.f = f;
    unsigned int r = v.u + 0x7fffu + ((v.u >> 16) & 1u);
    return (unsigned short)(r >> 16);
}
__device__ __forceinline__ float bf2f(unsigned short u) {
    union { unsigned int i; float f; } v; v.i = ((unsigned int)u) << 16; return v.f;
}

// async global->LDS 16B copy. LDS dest is wave-uniform base + lane*16.
__device__ __forceinline__ void lds_load16(void* lds, const void* gsrc) {
    __builtin_amdgcn_global_load_lds(
        (const __attribute__((address_space(1))) unsigned int*)gsrc,
        (__attribute__((address_space(3))) unsigned int*)lds,
        16, 0, 0);
}

// V permutation for PV A/B fragment layout: kv within 64-tile -> p slot.
__device__ __forceinline__ int vperm4(int kv4) {   // kv4 aligned to 4
    return ((kv4 >> 5) << 5) + (((kv4 >> 2) & 3) << 3) + (((kv4 >> 4) & 1) << 2);
}

// ================= fused prep kernel =================
__global__ __launch_bounds__(256) void prep_all(
    const float* __restrict__ x,  const float* __restrict__ Wq,
    const float* __restrict__ Wk, const float* __restrict__ Wv,
    const float* __restrict__ Wo,
    const float* __restrict__ kc, const float* __restrict__ vc,
    unsigned short* __restrict__ xbf, unsigned short* __restrict__ Wqb,
    unsigned short* __restrict__ Wkb, unsigned short* __restrict__ Wvb,
    unsigned short* __restrict__ Wob,
    float* __restrict__ kout, unsigned short* __restrict__ Kbf,
    float* __restrict__ vout, unsigned short* __restrict__ Vtp)
{
    const int bid = blockIdx.x;
    const int tid = threadIdx.x;

    if (bid < 24576) {
        int i = bid * 256 + tid;
        const float* src; unsigned short* dst; size_t off;
        if (i < 2097152) { src = x; dst = xbf; off = i; }
        else {
            int j = (i - 2097152) >> 20;
            off = (size_t)((i - 2097152) & 1048575);
            src = j == 0 ? Wq : j == 1 ? Wk : j == 2 ? Wv : Wo;
            dst = j == 0 ? Wqb : j == 1 ? Wkb : j == 2 ? Wvb : Wob;
        }
        f32x4 v = *(const f32x4*)(src + off * 4);
        ushort4 pk = { f2bf(v[0]), f2bf(v[1]), f2bf(v[2]), f2bf(v[3]) };
        *(ushort4*)(dst + off * 4) = pk;
    } else if (bid < 32768) {
        size_t i4 = (size_t)(bid - 24576) * 256 + tid;
        size_t e = i4 * 4;
        size_t bh = e >> 17, rem = e & 131071;
        f32x4 v = *(const f32x4*)(kc + e);
        size_t dsto = (bh << 18) + rem;
        *(f32x4*)(kout + dsto) = v;
        ushort4 pk = { f2bf(v[0]), f2bf(v[1]), f2bf(v[2]), f2bf(v[3]) };
        *(ushort4*)(Kbf + dsto) = pk;
    } else {
        __shared__ unsigned short T[128 * 72];
        const int o = bid - 32768;          // 0..1023
        const int t = o & 15;
        const int kv0 = t * 64;
        const int bh = o >> 4;
        const float* src = vc + ((size_t)bh << 17) + (size_t)kv0 * 128;
        float* vdst = vout + ((size_t)bh << 18) + (size_t)kv0 * 128;
        #pragma unroll
        for (int r = 0; r < 8; ++r) {
            int e4 = r * 256 + tid;
            int kv = e4 >> 5, d0 = (e4 & 31) << 2;
            f32x4 v = *(const f32x4*)(src + kv * 128 + d0);
            *(f32x4*)(vdst + kv * 128 + d0) = v;
            #pragma unroll
            for (int i = 0; i < 4; ++i) T[(d0 + i) * 72 + kv] = f2bf(v[i]);
        }
        __syncthreads();
        unsigned short* tile = Vtp + ((size_t)bh * 32 + t) * 8192;
        #pragma unroll
        for (int r = 0; r < 8; ++r) {
            int e = r * 256 + tid;
            int d = e >> 4, k4 = (e & 15) << 2;
            ushort4 pk = { T[d * 72 + k4], T[d * 72 + k4 + 1], T[d * 72 + k4 + 2], T[d * 72 + k4 + 3] };
            const int idx = d * 64 + (vperm4(k4) ^ ((d & 7) << 3));
            *(ushort4*)(tile + idx) = pk;
        }
    }
}

// ================= GEMM core: BK=32 (16KB LDS, max occupancy) + 2-way swizzle =====
// 128x128 tile, 4 waves (2x2). Round-11 structure (best measured: 30% occ) with
// bank-conflict fix: physical chunk q = g ^ ((row>>1)&3) spreads the 16 fragment
// rows over all 32 banks at exactly 2 lanes/bank (2-way = free, m136).
// Write side: pre-swizzled global source chunk (tid&3)^((tid>>3)&3), invariant
// across both 64-row issues; read side XOR ((c>>1)&3)*8 elems. Rule #21 both-sides.
__device__ __forceinline__ void gemm_core32s(
    const unsigned short* __restrict__ A16, const unsigned short* __restrict__ W16,
    int m0, int n0, int tid, int w, int g, int c, int wr, int wc,
    unsigned short* As, unsigned short* Bs, f32x4 (&acc)[4][4])
{
    const int arow = tid >> 2;                       // 0..63 (+64 for issue 1)
    const int achk = (tid & 3) ^ ((tid >> 3) & 3);   // pre-swizzled source chunk
    const unsigned short* Arow0 = A16 + (size_t)(m0 + arow) * DIMK + achk * 8;
    const unsigned short* Arow1 = A16 + (size_t)(m0 + 64 + arow) * DIMK + achk * 8;
    const unsigned short* Wrow0 = W16 + (size_t)(n0 + arow) * DIMK + achk * 8;
    const unsigned short* Wrow1 = W16 + (size_t)(n0 + 64 + arow) * DIMK + achk * 8;
    unsigned short* AsB0 = &As[(w * 64) * 8];
    unsigned short* AsB1 = &As[(256 + w * 64) * 8];
    unsigned short* BsB0 = &Bs[(w * 64) * 8];
    unsigned short* BsB1 = &Bs[(256 + w * 64) * 8];
    const int eswz = ((c >> 1) & 3) << 3;            // read-side XOR (elements)

    for (int k0 = 0; k0 < DIMK; k0 += 32) {
        __syncthreads();
        lds_load16(AsB0, Arow0 + k0);
        lds_load16(AsB1, Arow1 + k0);
        lds_load16(BsB0, Wrow0 + k0);
        lds_load16(BsB1, Wrow1 + k0);
        __syncthreads();

        const int ko = (g * 8) ^ eswz;
        bf16x8 af[4], bfr[4];
        #pragma unroll
        for (int i = 0; i < 4; ++i)
            af[i] = *(const bf16x8*)(&As[(wr * 64 + i * 16 + c) * 32 + ko]);
        #pragma unroll
        for (int i = 0; i < 4; ++i)
            bfr[i] = *(const bf16x8*)(&Bs[(wc * 64 + i * 16 + c) * 32 + ko]);
        #pragma unroll
        for (int i = 0; i < 4; ++i)
            #pragma unroll
            for (int j = 0; j < 4; ++j)
                acc[i][j] = __builtin_amdgcn_mfma_f32_16x16x32_bf16(af[i], bfr[j], acc[i][j], 0, 0, 0);
    }
}

// Fused Q/K/V projection GEMM. 1536 linear blocks, XCD-chunked n-panels.
__global__ __launch_bounds__(256) void gemm_qkv(
    const unsigned short* __restrict__ xbf,
    const unsigned short* __restrict__ Wqb, const unsigned short* __restrict__ Wkb,
    const unsigned short* __restrict__ Wvb,
    const float* __restrict__ bq, const float* __restrict__ bk, const float* __restrict__ bv,
    unsigned short* __restrict__ Qbf,
    float* __restrict__ kout, unsigned short* __restrict__ Kbf,
    float* __restrict__ vout, unsigned short* __restrict__ Vtp)
{
    const int o = blockIdx.x;
    const int xcd = o & 7;
    const int k = o >> 3;
    const int mblk = k & 31;
    const int nloc = k >> 5;
    const int nblk = xcd * 6 + nloc;
    const int m0 = mblk * 128;
    const int n0g = nblk * 128;
    const int mi = n0g >> 11;
    const int n0 = n0g & 2047;

    const unsigned short* W16 = mi == 0 ? Wqb : (mi == 1 ? Wkb : Wvb);
    const float* bias = mi == 0 ? bq : (mi == 1 ? bk : bv);

    const int tid = threadIdx.x;
    const int lane = tid & 63;
    const int w = tid >> 6;
    const int g = lane >> 4;
    const int c = lane & 15;
    const int wr = w >> 1, wc = w & 1;

    __shared__ unsigned short As[128 * 32];
    __shared__ unsigned short Bs[128 * 32];

    f32x4 acc[4][4];
    #pragma unroll
    for (int i = 0; i < 4; ++i)
        #pragma unroll
        for (int j = 0; j < 4; ++j)
            acc[i][j] = f32x4{0.f, 0.f, 0.f, 0.f};

    gemm_core32s(xbf, W16, m0, n0, tid, w, g, c, wr, wc, As, Bs, acc);

    #pragma unroll
    for (int j = 0; j < 4; ++j) {
        const int n = n0 + wc * 64 + j * 16 + c;
        const float bn = bias[n];
        const int hh = n >> 7, d = n & 127;
        #pragma unroll
        for (int i = 0; i < 4; ++i) {
            float y4[4];
            #pragma unroll
            for (int tq = 0; tq < 4; ++tq) y4[tq] = acc[i][j][tq] + bn;
            const int mb = m0 + wr * 64 + i * 16 + g * 4;
            if (mi == 0) {
                #pragma unroll
                for (int tq = 0; tq < 4; ++tq) {
                    int m = mb + tq; int b = m >> 10, s = m & 1023;
                    Qbf[((((size_t)b * 16 + hh) << 10) + s) * 128 + d] = f2bf(y4[tq] * QSCALE);
                }
            } else if (mi == 1) {
                #pragma unroll
                for (int tq = 0; tq < 4; ++tq) {
                    int m = mb + tq; int b = m >> 10, s = m & 1023;
                    kout[(((size_t)b * 16 + hh) * 2048 + 1024 + s) * 128 + d] = y4[tq];
                    Kbf[(((size_t)b * 16 + hh) << 18) + (size_t)(1024 + s) * 128 + d] = f2bf(y4[tq]);
                }
            } else {
                #pragma unroll
                for (int tq = 0; tq < 4; ++tq) {
                    int m = mb + tq; int b = m >> 10, s = m & 1023;
                    vout[(((size_t)b * 16 + hh) * 2048 + 1024 + s) * 128 + d] = y4[tq];
                }
                int b = mb >> 10, s = mb & 1023;
                const int t = 16 + (s >> 6);
                const int idx = d * 64 + (vperm4(s & 63) ^ ((d & 7) << 3));
                ushort4 pk = { f2bf(y4[0]), f2bf(y4[1]), f2bf(y4[2]), f2bf(y4[3]) };
                *(ushort4*)(Vtp + ((size_t)(b * 16 + hh) * 32 + t) * 8192 + idx) = pk;
            }
        }
    }
}

// Output projection GEMM: 512 linear blocks, XCD-chunked.
__global__ __launch_bounds__(256) void gemm_wo(
    const unsigned short* __restrict__ ctx, const unsigned short* __restrict__ Wob,
    const float* __restrict__ bo, float* __restrict__ outp)
{
    const int o = blockIdx.x;
    const int xcd = o & 7;
    const int k = o >> 3;
    const int mblk = k & 31;
    const int nloc = k >> 5;
    const int nblk = xcd * 2 + nloc;
    const int m0 = mblk * 128;
    const int n0 = nblk * 128;

    const int tid = threadIdx.x;
    const int lane = tid & 63;
    const int w = tid >> 6;
    const int g = lane >> 4;
    const int c = lane & 15;
    const int wr = w >> 1, wc = w & 1;

    __shared__ unsigned short As[128 * 32];
    __shared__ unsigned short Bs[128 * 32];

    f32x4 acc[4][4];
    #pragma unroll
    for (int i = 0; i < 4; ++i)
        #pragma unroll
        for (int j = 0; j < 4; ++j)
            acc[i][j] = f32x4{0.f, 0.f, 0.f, 0.f};

    gemm_core32s(ctx, Wob, m0, n0, tid, w, g, c, wr, wc, As, Bs, acc);

    #pragma unroll
    for (int j = 0; j < 4; ++j) {
        const int n = n0 + wc * 64 + j * 16 + c;
        const float bn = bo[n];
        #pragma unroll
        for (int i = 0; i < 4; ++i) {
            const int mb = m0 + wr * 64 + i * 16 + g * 4;
            #pragma unroll
            for (int tq = 0; tq < 4; ++tq)
                outp[(size_t)(mb + tq) * 2048 + n] = acc[i][j][tq] + bn;
        }
    }
}

// ================= flash attention v9: 8 waves x 16 q-rows, all-DMA staging ==========
// (unchanged, known-good: ~110us, 16 waves/CU)
__global__ __launch_bounds__(512) void attn9(
    const unsigned short* __restrict__ Qbf,   // [B,H,1024,128] pre-scaled
    const unsigned short* __restrict__ Kbf,   // [B,H,2048,128]
    const unsigned short* __restrict__ Vtp,   // [B,H,32,8192] baked LDS images
    unsigned short* __restrict__ Pp,          // [2][64][1024][128] bf16 partials
    float* __restrict__ Mp,                   // [2][64][1024]
    float* __restrict__ Lp)                   // [2][64][1024]
{
    const int o = blockIdx.x;
    const int xcd = o & 7;
    const int kk0 = o >> 3;
    const int half = kk0 & 1;
    const int qt = 7 - ((kk0 >> 1) & 7);      // heavy-first
    const int bh = (kk0 >> 4) * 8 + xcd;

    const int tid = threadIdx.x;              // 0..511
    const int lane = tid & 63;
    const int w = tid >> 6;                   // 0..7
    const int g = lane >> 4;
    const int c = lane & 15;
    const int cswz = (c & 7) << 3;

    __shared__ unsigned short Ks[2][64 * 128];   // 32 KB
    __shared__ unsigned short Vs[2][64 * 128];   // 32 KB ([d][p] image)

    const unsigned short* Qb = Qbf + ((size_t)bh * 1024 + qt * 128) * 128;
    const unsigned short* Kb = Kbf + ((size_t)bh << 18);
    const unsigned short* Vtile = Vtp + (size_t)bh * 32 * 8192;

    bf16x8 aq[4];
    #pragma unroll
    for (int kd = 0; kd < 4; ++kd)
        aq[kd] = *(const bf16x8*)(Qb + (w * 16 + c) * 128 + kd * 32 + g * 8);

    f32x4 od[8];
    #pragma unroll
    for (int nf = 0; nf < 8; ++nf)
        od[nf] = f32x4{0.f, 0.f, 0.f, 0.f};
    float mrow = -1e30f, lrow = 0.f;

    const int krow = tid >> 4;
    const int kswz = (((tid & 15) << 4) ^ ((krow & 7) << 4)) >> 1;
    const unsigned short* Kl = Kb + (size_t)krow * 128 + kswz;

    const int cnt = 9 + qt;
    const int t0 = half * cnt;
    const int limw = 1024 + qt * 128 + w * 16;

    {
        const int kv0 = t0 * 64;
        lds_load16(&Ks[0][w * 512], Kl + (size_t)kv0 * 128);
        lds_load16(&Ks[0][4096 + w * 512], Kl + (size_t)(kv0 + 32) * 128);
        const unsigned short* Vsrc = Vtile + (size_t)t0 * 8192 + tid * 8;
        lds_load16(&Vs[0][w * 512], Vsrc);
        lds_load16(&Vs[0][4096 + w * 512], Vsrc + 4096);
        __syncthreads();
    }

    int cur = 0;
    for (int t = t0; t < t0 + cnt; ++t) {
        const int kv0 = t * 64;
        const bool next = (t + 1 < t0 + cnt);

        if (next) {
            const int kvn = kv0 + 64;
            lds_load16(&Ks[cur ^ 1][w * 512], Kl + (size_t)kvn * 128);
            lds_load16(&Ks[cur ^ 1][4096 + w * 512], Kl + (size_t)(kvn + 32) * 128);
            const unsigned short* Vsrc = Vtile + (size_t)(t + 1) * 8192 + tid * 8;
            lds_load16(&Vs[cur ^ 1][w * 512], Vsrc);
            lds_load16(&Vs[cur ^ 1][4096 + w * 512], Vsrc + 4096);
        }

        const unsigned short* Ksc = &Ks[cur][0];
        const unsigned short* Vsc = &Vs[cur][0];

        f32x4 sc[4];
        #pragma unroll
        for (int n = 0; n < 4; ++n)
            sc[n] = f32x4{0.f, 0.f, 0.f, 0.f};
        #pragma unroll
        for (int kd = 0; kd < 4; ++kd) {
            bf16x8 bk[4];
            #pragma unroll
            for (int n = 0; n < 4; ++n)
                bk[n] = *(const bf16x8*)(&Ksc[(n * 16 + c) * 128 + ((kd * 32 + g * 8) ^ cswz)]);
            #pragma unroll
            for (int n = 0; n < 4; ++n)
                sc[n] = __builtin_amdgcn_mfma_f32_16x16x32_bf16(bk[n], aq[kd], sc[n], 0, 0, 0);
        }

        const bool need_mask = (kv0 + 63 > limw);
        if (need_mask) {
            const int lim = limw + c;
            #pragma unroll
            for (int n = 0; n < 4; ++n)
                #pragma unroll
                for (int j = 0; j < 4; ++j)
                    if (kv0 + n * 16 + g * 4 + j > lim) sc[n][j] = -1e30f;
        }
        {
            float t4[4];
            #pragma unroll
            for (int n = 0; n < 4; ++n)
                t4[n] = fmaxf(fmaxf(sc[n][0], sc[n][1]), fmaxf(sc[n][2], sc[n][3]));
            float rmax = fmaxf(fmaxf(t4[0], t4[1]), fmaxf(t4[2], t4[3]));
            rmax = fmaxf(rmax, __shfl_xor(rmax, 16));
            rmax = fmaxf(rmax, __shfl_xor(rmax, 32));

            if (!__all(rmax <= mrow + 8.0f)) {
                const float mnew = fmaxf(mrow, rmax);
                const float fs = exp2f(mrow - mnew);
                mrow = mnew;
                lrow *= fs;
                #pragma unroll
                for (int j = 0; j < 4; ++j) {
                    const float fsj = __shfl(fs, (lane & 48) | (g * 4 + j));
                    #pragma unroll
                    for (int nf = 0; nf < 8; ++nf)
                        od[nf][j] *= fsj;
                }
            }
            const float mm = mrow;
            float s4[4];
            #pragma unroll
            for (int n = 0; n < 4; ++n) {
                #pragma unroll
                for (int j = 0; j < 4; ++j)
                    sc[n][j] = exp2f(sc[n][j] - mm);
                s4[n] = (sc[n][0] + sc[n][1]) + (sc[n][2] + sc[n][3]);
            }
            float rsum = (s4[0] + s4[1]) + (s4[2] + s4[3]);
            rsum += __shfl_xor(rsum, 16);
            rsum += __shfl_xor(rsum, 32);
            lrow += rsum;
        }

        bf16x8 pa[2];
        #pragma unroll
        for (int kk = 0; kk < 2; ++kk)
            #pragma unroll
            for (int e = 0; e < 8; ++e)
                pa[kk][e] = (__bf16)sc[2 * kk + (e >> 2)][e & 3];

        #pragma unroll
        for (int kk = 0; kk < 2; ++kk) {
            #pragma unroll
            for (int nf = 0; nf < 8; ++nf) {
                bf16x8 bv = *(const bf16x8*)(&Vsc[(nf * 16 + c) * 64 + ((kk * 32 + g * 8) ^ cswz)]);
                od[nf] = __builtin_amdgcn_mfma_f32_16x16x32_bf16(pa[kk], bv, od[nf], 0, 0, 0);
            }
        }

        __syncthreads();
        cur ^= 1;
    }

    const size_t pbase = ((size_t)(half * 64 + bh) * 1024 + qt * 128) * 128;
    const int mlbase = (half * 64 + bh) * 1024 + qt * 128;
    if (lane < 16) {
        Mp[mlbase + w * 16 + c] = mrow;
        Lp[mlbase + w * 16 + c] = lrow;
    }
    #pragma unroll
    for (int j = 0; j < 4; ++j) {
        const float lj = __shfl(lrow, (lane & 48) | (g * 4 + j));
        const float rl = 1.0f / lj;
        const int ql = w * 16 + g * 4 + j;
        #pragma unroll
        for (int nf = 0; nf < 8; ++nf)
            Pp[pbase + (size_t)ql * 128 + nf * 16 + c] = f2bf(od[nf][j] * rl);
    }
}

// merge the two KV-split partials -> ctx bf16
__global__ __launch_bounds__(256) void merge_ctx(
    const unsigned short* __restrict__ Pp, const float* __restrict__ Mp,
    const float* __restrict__ Lp, unsigned short* __restrict__ ctx)
{
    const int idx = blockIdx.x * 256 + threadIdx.x;
    const int r = idx >> 4;
    const int dc = (idx & 15) << 3;
    const float m0 = Mp[r], m1 = Mp[65536 + r];
    const float l0 = Lp[r], l1 = Lp[65536 + r];
    const float M = fmaxf(m0, m1);
    float w0 = l0 * exp2f(m0 - M);
    float w1 = l1 * exp2f(m1 - M);
    const float inv = 1.0f / (w0 + w1);
    w0 *= inv; w1 *= inv;
    u16x8 a = *(const u16x8*)(Pp + (size_t)r * 128 + dc);
    u16x8 bb = *(const u16x8*)(Pp + (size_t)8388608 + (size_t)r * 128 + dc);
    const int bh = r >> 10, q = r & 1023;
    unsigned short* dst = ctx + ((size_t)(bh >> 4) * 1024 + q) * 2048 + (bh & 15) * 128 + dc;
    u16x8 outv;
    #pragma unroll
    for (int e = 0; e < 8; ++e)
        outv[e] = f2bf(w0 * bf2f(a[e]) + w1 * bf2f(bb[e]));
    *(u16x8*)dst = outv;
}

// ================= small-ws fallback =================
__global__ __launch_bounds__(256) void copy_cache(
    const float* __restrict__ kc, const float* __restrict__ vc,
    float* __restrict__ kout, float* __restrict__ vout)
{
    size_t i4 = (size_t)blockIdx.x * 256 + threadIdx.x;
    const float* src = blockIdx.y ? vc : kc;
    float* dst = blockIdx.y ? vout : kout;
    size_t e = i4 * 4;
    size_t bh = e >> 17, rem = e & 131071;
    f32x4 v = *(const f32x4*)(src + e);
    *(f32x4*)(dst + (bh << 18) + rem) = v;
}

template<int MODE, bool ABF16>
__global__ __launch_bounds__(256) void gemm_bt(
    const void* __restrict__ Ag, const float* __restrict__ Wf,
    const float* __restrict__ bias, void* __restrict__ dst)
{
    const int tid = threadIdx.x;
    const int lane = tid & 63;
    const int w = tid >> 6;
    const int g = lane >> 4;
    const int c = lane & 15;
    const int wr = w >> 1, wc = w & 1;
    const int m0 = blockIdx.y * 128;
    const int n0 = blockIdx.x * 128;

    __shared__ unsigned short As[128 * 40];
    __shared__ unsigned short Bs[128 * 40];

    f32x4 acc[4][4];
    #pragma unroll
    for (int i = 0; i < 4; ++i)
        #pragma unroll
        for (int j = 0; j < 4; ++j)
            acc[i][j] = f32x4{0.f, 0.f, 0.f, 0.f};

    for (int k0 = 0; k0 < DIMK; k0 += 32) {
        __syncthreads();
        if constexpr (ABF16) {
            const unsigned short* A16 = (const unsigned short*)Ag;
            #pragma unroll
            for (int r = 0; r < 2; ++r) {
                int e8 = r * 256 + tid;
                int row = e8 >> 2, col = (e8 & 3) << 3;
                *(uint4*)(&As[row * 40 + col]) =
                    *(const uint4*)(A16 + (size_t)(m0 + row) * DIMK + k0 + col);
            }
        } else {
            const float* Af = (const float*)Ag;
            #pragma unroll
            for (int r = 0; r < 4; ++r) {
                int e4 = r * 256 + tid;
                int row = e4 >> 3, col = (e4 & 7) << 2;
                f32x4 v = *(const f32x4*)(Af + (size_t)(m0 + row) * DIMK + k0 + col);
                ushort4 pk = { f2bf(v[0]), f2bf(v[1]), f2bf(v[2]), f2bf(v[3]) };
                *(ushort4*)(&As[row * 40 + col]) = pk;
            }
        }
        {
            #pragma unroll
            for (int r = 0; r < 4; ++r) {
                int e4 = r * 256 + tid;
                int row = e4 >> 3, col = (e4 & 7) << 2;
                f32x4 v = *(const f32x4*)(Wf + (size_t)(n0 + row) * DIMK + k0 + col);
                ushort4 pk = { f2bf(v[0]), f2bf(v[1]), f2bf(v[2]), f2bf(v[3]) };
                *(ushort4*)(&Bs[row * 40 + col]) = pk;
            }
        }
        __syncthreads();

        bf16x8 af[4], bfr[4];
        #pragma unroll
        for (int i = 0; i < 4; ++i)
            af[i] = *(const bf16x8*)(&As[(wr * 64 + i * 16 + c) * 40 + g * 8]);
        #pragma unroll
        for (int i = 0; i < 4; ++i)
            bfr[i] = *(const bf16x8*)(&Bs[(wc * 64 + i * 16 + c) * 40 + g * 8]);
        #pragma unroll
        for (int i = 0; i < 4; ++i)
            #pragma unroll
            for (int j = 0; j < 4; ++j)
                acc[i][j] = __builtin_amdgcn_mfma_f32_16x16x32_bf16(af[i], bfr[j], acc[i][j], 0, 0, 0);
    }

    #pragma unroll
    for (int j = 0; j < 4; ++j) {
        const int n = n0 + wc * 64 + j * 16 + c;
        const float bn = bias[n];
        #pragma unroll
        for (int i = 0; i < 4; ++i) {
            float y4[4];
            #pragma unroll
            for (int tq = 0; tq < 4; ++tq) y4[tq] = acc[i][j][tq] + bn;
            const int mb = m0 + wr * 64 + i * 16 + g * 4;
            if constexpr (MODE == 0) {
                #pragma unroll
                for (int tq = 0; tq < 4; ++tq) {
                    int m = mb + tq; int b = m >> 10, s = m & 1023;
                    int hh = n >> 7, d = n & 127;
                    ((unsigned short*)dst)[((((size_t)b * 16 + hh) << 10) + s) * 128 + d] = f2bf(y4[tq] * QSCALE);
                }
            } else if constexpr (MODE == 1) {
                #pragma unroll
                for (int tq = 0; tq < 4; ++tq) {
                    int m = mb + tq; int b = m >> 10, s = m & 1023;
                    int hh = n >> 7, d = n & 127;
                    ((float*)dst)[(((size_t)b * 16 + hh) * 2048 + 1024 + s) * 128 + d] = y4[tq];
                }
            } else {
                #pragma unroll
                for (int tq = 0; tq < 4; ++tq)
                    ((float*)dst)[(size_t)(mb + tq) * 2048 + n] = y4[tq];
            }
        }
    }
}

__global__ __launch_bounds__(256) void attn_stage(
    const unsigned short* __restrict__ Qbf,
    const float* __restrict__ Kf, const float* __restrict__ Vf,
    unsigned short* __restrict__ ctx)
{
    const int qt = blockIdx.x;
    const int bh = blockIdx.y;
    const int b = bh >> 4, h = bh & 15;
    const int tid = threadIdx.x;
    const int lane = tid & 63;
    const int w = tid >> 6;
    const int g = lane >> 4;
    const int c = lane & 15;

    __shared__ unsigned short Ksl[64 * 136];
    __shared__ unsigned short Vtl[128 * 72];
    __shared__ unsigned short Ps[4 * 32 * 72];

    bf16x8 aq[2][4];
    const unsigned short* Qb = Qbf + ((size_t)bh * 1024 + qt * 128) * 128;
    #pragma unroll
    for (int m2 = 0; m2 < 2; ++m2)
        #pragma unroll
        for (int kk = 0; kk < 4; ++kk)
            aq[m2][kk] = *(const bf16x8*)(Qb + (w * 32 + m2 * 16 + c) * 128 + kk * 32 + g * 8);

    f32x4 od[2][8];
    #pragma unroll
    for (int m2 = 0; m2 < 2; ++m2)
        #pragma unroll
        for (int nf = 0; nf < 8; ++nf)
            od[m2][nf] = f32x4{0.f, 0.f, 0.f, 0.f};
    float mrow[2][4], lrow[2][4];
    #pragma unroll
    for (int m2 = 0; m2 < 2; ++m2)
        #pragma unroll
        for (int j = 0; j < 4; ++j) { mrow[m2][j] = -1e30f; lrow[m2][j] = 0.f; }

    const float* Kb = Kf + (size_t)bh * 2048 * 128;
    const float* Vb = Vf + (size_t)bh * 2048 * 128;
    const int ntiles = 18 + 2 * qt;

    for (int t = 0; t < ntiles; ++t) {
        __syncthreads();
        const float* Kt = Kb + (size_t)t * 64 * 128;
        #pragma unroll
        for (int r = 0; r < 8; ++r) {
            int e4 = r * 256 + tid;
            int kv = e4 >> 5, d0 = (e4 & 31) << 2;
            f32x4 v = *(const f32x4*)(Kt + kv * 128 + d0);
            ushort4 pk = { f2bf(v[0]), f2bf(v[1]), f2bf(v[2]), f2bf(v[3]) };
            *(ushort4*)(&Ksl[kv * 136 + d0]) = pk;
        }
        const float* Vg = Vb + (size_t)t * 64 * 128;
        #pragma unroll
        for (int r = 0; r < 8; ++r) {
            int e4 = tid * 8 + r;
            int kv = e4 >> 5, d0 = (e4 & 31) << 2;
            f32x4 v = *(const f32x4*)(Vg + kv * 128 + d0);
            #pragma unroll
            for (int i = 0; i < 4; ++i)
                Vtl[(d0 + i) * 72 + kv] = f2bf(v[i]);
        }
        __syncthreads();

        f32x4 sc[2][4];
        #pragma unroll
        for (int m2 = 0; m2 < 2; ++m2)
            #pragma unroll
            for (int n = 0; n < 4; ++n)
                sc[m2][n] = f32x4{0.f, 0.f, 0.f, 0.f};
        #pragma unroll
        for (int kk = 0; kk < 4; ++kk) {
            bf16x8 bk[4];
            #pragma unroll
            for (int n = 0; n < 4; ++n)
                bk[n] = *(const bf16x8*)(&Ksl[(n * 16 + c) * 136 + kk * 32 + g * 8]);
            #pragma unroll
            for (int m2 = 0; m2 < 2; ++m2)
                #pragma unroll
                for (int n = 0; n < 4; ++n)
                    sc[m2][n] = __builtin_amdgcn_mfma_f32_16x16x32_bf16(aq[m2][kk], bk[n], sc[m2][n], 0, 0, 0);
        }

        const int kvbase = t * 64;
        #pragma unroll
        for (int m2 = 0; m2 < 2; ++m2) {
            #pragma unroll
            for (int j = 0; j < 4; ++j) {
                const int qg = qt * 128 + w * 32 + m2 * 16 + g * 4 + j;
                const int lim = qg + 1024;
                float rmax = -1e30f;
                #pragma unroll
                for (int n = 0; n < 4; ++n) {
                    float s = sc[m2][n][j] * QSCALE;
                    if (kvbase + n * 16 + c > lim) s = -1e30f;
                    sc[m2][n][j] = s;
                    rmax = fmaxf(rmax, s);
                }
                #pragma unroll
                for (int off = 1; off < 16; off <<= 1)
                    rmax = fmaxf(rmax, __shfl_xor(rmax, off));
                float mold = mrow[m2][j];
                float mnew = fmaxf(mold, rmax);
                mrow[m2][j] = mnew;
                float fs = exp2f(mold - mnew);
                float rsum = 0.f;
                #pragma unroll
                for (int n = 0; n < 4; ++n) {
                    float p = exp2f(sc[m2][n][j] - mnew);
                    sc[m2][n][j] = p;
                    rsum += p;
                }
                #pragma unroll
                for (int off = 1; off < 16; off <<= 1)
                    rsum += __shfl_xor(rsum, off);
                lrow[m2][j] = lrow[m2][j] * fs + rsum;
                #pragma unroll
                for (int nf = 0; nf < 8; ++nf)
                    od[m2][nf][j] *= fs;
            }
        }

        unsigned short* Pw = &Ps[w * 32 * 72];
        #pragma unroll
        for (int m2 = 0; m2 < 2; ++m2)
            #pragma unroll
            for (int n = 0; n < 4; ++n)
                #pragma unroll
                for (int j = 0; j < 4; ++j)
                    Pw[(m2 * 16 + g * 4 + j) * 72 + n * 16 + c] = f2bf(sc[m2][n][j]);

        #pragma unroll
        for (int kk = 0; kk < 2; ++kk) {
            bf16x8 ap0 = *(const bf16x8*)(&Ps[(w * 32 + c) * 72 + kk * 32 + g * 8]);
            bf16x8 ap1 = *(const bf16x8*)(&Ps[(w * 32 + 16 + c) * 72 + kk * 32 + g * 8]);
            #pragma unroll
            for (int nf = 0; nf < 8; ++nf) {
                bf16x8 bv = *(const bf16x8*)(&Vtl[(nf * 16 + c) * 72 + kk * 32 + g * 8]);
                od[0][nf] = __builtin_amdgcn_mfma_f32_16x16x32_bf16(ap0, bv, od[0][nf], 0, 0, 0);
                od[1][nf] = __builtin_amdgcn_mfma_f32_16x16x32_bf16(ap1, bv, od[1][nf], 0, 0, 0);
            }
        }
    }

    #pragma unroll
    for (int m2 = 0; m2 < 2; ++m2) {
        #pragma unroll
        for (int j = 0; j < 4; ++j) {
            const int qg = qt * 128 + w * 32 + m2 * 16 + g * 4 + j;
            const float rl = 1.0f / lrow[m2][j];
            #pragma unroll
            for (int nf = 0; nf < 8; ++nf) {
                const int d = nf * 16 + c;
                ctx[((size_t)b * 1024 + qg) * 2048 + h * 128 + d] = f2bf(od[m2][nf][j] * rl);
            }
        }
    }
}

extern "C" void kernel_launch(void* const* d_in, const int* in_sizes, int n_in,
                              void* d_out, int out_size, void* d_ws, size_t ws_size,
                              hipStream_t stream) {
    const float* x  = (const float*)d_in[0];
    const float* kc = (const float*)d_in[1];
    const float* vc = (const float*)d_in[2];
    const float* Wq = (const float*)d_in[3];
    const float* bq = (const float*)d_in[4];
    const float* Wk = (const float*)d_in[5];
    const float* bk = (const float*)d_in[6];
    const float* Wv = (const float*)d_in[7];
    const float* bv = (const float*)d_in[8];
    const float* Wo = (const float*)d_in[9];
    const float* bo = (const float*)d_in[10];

    float* outp = (float*)d_out;
    float* kout = outp + (size_t)8388608;
    float* vout = outp + (size_t)25165824;

    unsigned short* Qbf = (unsigned short*)d_ws;          //  8,388,608
    unsigned short* ctx = Qbf + (size_t)8388608;          //  8,388,608
    unsigned short* Kbf = ctx + (size_t)8388608;          // 16,777,216
    unsigned short* Vtp = Kbf + (size_t)16777216;         // 16,777,216 (baked V images)
    unsigned short* xbf = Vtp + (size_t)16777216;         //  8,388,608
    unsigned short* Wqb = xbf + (size_t)8388608;
    unsigned short* Wkb = Wqb + (size_t)4194304;
    unsigned short* Wvb = Wkb + (size_t)4194304;
    unsigned short* Wob = Wvb + (size_t)4194304;
    unsigned short* Pp = xbf;                             // reuse xbf+Wqb+Wkb
    float* Mp = (float*)Wvb;
    float* Lp = Mp + (size_t)131072;

    const bool full = ws_size >= (size_t)150994944;

    if (full) {
        prep_all<<<33792, 256, 0, stream>>>(x, Wq, Wk, Wv, Wo, kc, vc,
                                            xbf, Wqb, Wkb, Wvb, Wob,
                                            kout, Kbf, vout, Vtp);
        gemm_qkv<<<1536, 256, 0, stream>>>(xbf, Wqb, Wkb, Wvb, bq, bk, bv,
                                           Qbf, kout, Kbf, vout, Vtp);
        attn9<<<1024, 512, 0, stream>>>(Qbf, Kbf, Vtp, Pp, Mp, Lp);
        merge_ctx<<<4096, 256, 0, stream>>>(Pp, Mp, Lp, ctx);
        gemm_wo<<<512, 256, 0, stream>>>(ctx, Wob, bo, outp);
    } else {
        copy_cache<<<dim3(8192, 2), 256, 0, stream>>>(kc, vc, kout, vout);
        gemm_bt<0, false><<<dim3(16, 32), 256, 0, stream>>>(x, Wq, bq, Qbf);
        gemm_bt<1, false><<<dim3(16, 32), 256, 0, stream>>>(x, Wk, bk, kout);
        gemm_bt<1, false><<<dim3(16, 32), 256, 0, stream>>>(x, Wv, bv, vout);
        attn_stage<<<dim3(8, 64), 256, 0, stream>>>(Qbf, kout, vout, ctx);
        gemm_bt<2, true><<<dim3(16, 32), 256, 0, stream>>>(ctx, Wo, bo, outp);
    }
}

// Round 16
// 366.970 us; speedup vs baseline: 1.1018x; 1.0269x over previous
//
#include <hip/hip_runtime.h>
#include <hip/hip_bf16.h>

typedef float f32x4 __attribute__((ext_vector_type(4)));
typedef __bf16 bf16x8 __attribute__((ext_vector_type(8)));
typedef unsigned short u16x8 __attribute__((ext_vector_type(8)));

// ---- constants: B=4, S=1024, dim=2048, H=16, D=128, T=1024, KV=2048, M=4096
#define DIMK 2048
#define QSCALE ((float)(0.08838834764831845 * 1.4426950408889634))  // 1/sqrt(128)*log2(e)

__device__ __forceinline__ unsigned short f2bf(float f) {
    union { float f; unsigned int u; } v; v.f = f;
    unsigned int r = v.u + 0x7fffu + ((v.u >> 16) & 1u);
    return (unsigned short)(r >> 16);
}
__device__ __forceinline__ float bf2f(unsigned short u) {
    union { unsigned int i; float f; } v; v.i = ((unsigned int)u) << 16; return v.f;
}

// async global->LDS 16B copy. LDS dest is wave-uniform base + lane*16.
__device__ __forceinline__ void lds_load16(void* lds, const void* gsrc) {
    __builtin_amdgcn_global_load_lds(
        (const __attribute__((address_space(1))) unsigned int*)gsrc,
        (__attribute__((address_space(3))) unsigned int*)lds,
        16, 0, 0);
}

// V permutation for PV A/B fragment layout: kv within 64-tile -> p slot.
// kv = kk*32 + a*16 + gv*4 + j  ->  p = kk*32 + gv*8 + a*4 + j  (j preserved)
__device__ __forceinline__ int vperm4(int kv4) {   // kv4 aligned to 4
    return ((kv4 >> 5) << 5) + (((kv4 >> 2) & 3) << 3) + (((kv4 >> 4) & 1) << 2);
}

// ================= fused prep kernel =================
// blocks 0..24575     : conv (x + 4 weights) -> bf16
// blocks 24576..32767 : k_dual (k_cache -> kout fp32 + Kbf bf16)
// blocks 32768..33791 : v_dual (v_cache -> vout fp32 + Vtp baked-LDS-image bf16)
// Vtp layout: [bh][tile t=kv/64][d*64 + (vperm(kv&63) ^ ((d&7)<<3))]  (16KB per tile)
__global__ __launch_bounds__(256) void prep_all(
    const float* __restrict__ x,  const float* __restrict__ Wq,
    const float* __restrict__ Wk, const float* __restrict__ Wv,
    const float* __restrict__ Wo,
    const float* __restrict__ kc, const float* __restrict__ vc,
    unsigned short* __restrict__ xbf, unsigned short* __restrict__ Wqb,
    unsigned short* __restrict__ Wkb, unsigned short* __restrict__ Wvb,
    unsigned short* __restrict__ Wob,
    float* __restrict__ kout, unsigned short* __restrict__ Kbf,
    float* __restrict__ vout, unsigned short* __restrict__ Vtp)
{
    const int bid = blockIdx.x;
    const int tid = threadIdx.x;

    if (bid < 24576) {
        int i = bid * 256 + tid;
        const float* src; unsigned short* dst; size_t off;
        if (i < 2097152) { src = x; dst = xbf; off = i; }
        else {
            int j = (i - 2097152) >> 20;
            off = (size_t)((i - 2097152) & 1048575);
            src = j == 0 ? Wq : j == 1 ? Wk : j == 2 ? Wv : Wo;
            dst = j == 0 ? Wqb : j == 1 ? Wkb : j == 2 ? Wvb : Wob;
        }
        f32x4 v = *(const f32x4*)(src + off * 4);
        ushort4 pk = { f2bf(v[0]), f2bf(v[1]), f2bf(v[2]), f2bf(v[3]) };
        *(ushort4*)(dst + off * 4) = pk;
    } else if (bid < 32768) {
        size_t i4 = (size_t)(bid - 24576) * 256 + tid;
        size_t e = i4 * 4;
        size_t bh = e >> 17, rem = e & 131071;
        f32x4 v = *(const f32x4*)(kc + e);
        size_t dsto = (bh << 18) + rem;
        *(f32x4*)(kout + dsto) = v;
        ushort4 pk = { f2bf(v[0]), f2bf(v[1]), f2bf(v[2]), f2bf(v[3]) };
        *(ushort4*)(Kbf + dsto) = pk;
    } else {
        __shared__ unsigned short T[128 * 72];
        const int o = bid - 32768;          // 0..1023
        const int t = o & 15;               // tile (cache rows 0..1023 -> tiles 0..15)
        const int kv0 = t * 64;
        const int bh = o >> 4;
        const float* src = vc + ((size_t)bh << 17) + (size_t)kv0 * 128;
        float* vdst = vout + ((size_t)bh << 18) + (size_t)kv0 * 128;
        #pragma unroll
        for (int r = 0; r < 8; ++r) {
            int e4 = r * 256 + tid;
            int kv = e4 >> 5, d0 = (e4 & 31) << 2;
            f32x4 v = *(const f32x4*)(src + kv * 128 + d0);
            *(f32x4*)(vdst + kv * 128 + d0) = v;
            #pragma unroll
            for (int i = 0; i < 4; ++i) T[(d0 + i) * 72 + kv] = f2bf(v[i]);
        }
        __syncthreads();
        unsigned short* tile = Vtp + ((size_t)bh * 32 + t) * 8192;
        #pragma unroll
        for (int r = 0; r < 8; ++r) {
            int e = r * 256 + tid;
            int d = e >> 4, k4 = (e & 15) << 2;
            ushort4 pk = { T[d * 72 + k4], T[d * 72 + k4 + 1], T[d * 72 + k4 + 2], T[d * 72 + k4 + 3] };
            const int idx = d * 64 + (vperm4(k4) ^ ((d & 7) << 3));
            *(ushort4*)(tile + idx) = pk;
        }
    }
}

// ================= GEMM core: BK=64, XOR-swizzled LDS (round-13 best-total) =====
// 128x128 tile, 4 waves (2x2), BK=64. LDS 2 x 16KB, one barrier pair per 64-K.
// Swizzle: LDS[row][chunk q] holds global[row][q ^ (row&7)] (8-elem chunks);
// staged via pre-swizzled global source, read with matching XOR (rule #21).
__device__ __forceinline__ void gemm_core64(
    const unsigned short* __restrict__ A16, const unsigned short* __restrict__ W16,
    int m0, int n0, int tid, int w, int g, int c, int wr, int wc,
    unsigned short* As, unsigned short* Bs, f32x4 (&acc)[4][4])
{
    const int srow = tid >> 3;                 // 0..31 (issue r adds 32)
    const int schk = (tid & 7) ^ (srow & 7);   // pre-swizzled source chunk
    const unsigned short* Asrc = A16 + (size_t)(m0 + srow) * DIMK + schk * 8;
    const unsigned short* Bsrc = W16 + (size_t)(n0 + srow) * DIMK + schk * 8;
    const int cswz = (c & 7) << 3;

    for (int k0 = 0; k0 < DIMK; k0 += 64) {
        __syncthreads();
        #pragma unroll
        for (int r = 0; r < 4; ++r) {
            lds_load16(As + r * 2048 + w * 512, Asrc + (size_t)r * 32 * DIMK + k0);
            lds_load16(Bs + r * 2048 + w * 512, Bsrc + (size_t)r * 32 * DIMK + k0);
        }
        __syncthreads();

        #pragma unroll
        for (int kd = 0; kd < 2; ++kd) {
            const int ko = (kd * 32 + g * 8) ^ cswz;
            bf16x8 af[4], bfr[4];
            #pragma unroll
            for (int i = 0; i < 4; ++i)
                af[i] = *(const bf16x8*)(&As[(wr * 64 + i * 16 + c) * 64 + ko]);
            #pragma unroll
            for (int i = 0; i < 4; ++i)
                bfr[i] = *(const bf16x8*)(&Bs[(wc * 64 + i * 16 + c) * 64 + ko]);
            #pragma unroll
            for (int i = 0; i < 4; ++i)
                #pragma unroll
                for (int j = 0; j < 4; ++j)
                    acc[i][j] = __builtin_amdgcn_mfma_f32_16x16x32_bf16(af[i], bfr[j], acc[i][j], 0, 0, 0);
        }
    }
}

// Fused Q/K/V projection GEMM. 1536 linear blocks, XCD-chunked n-panels.
__global__ __launch_bounds__(256) void gemm_qkv(
    const unsigned short* __restrict__ xbf,
    const unsigned short* __restrict__ Wqb, const unsigned short* __restrict__ Wkb,
    const unsigned short* __restrict__ Wvb,
    const float* __restrict__ bq, const float* __restrict__ bk, const float* __restrict__ bv,
    unsigned short* __restrict__ Qbf,
    float* __restrict__ kout, unsigned short* __restrict__ Kbf,
    float* __restrict__ vout, unsigned short* __restrict__ Vtp)
{
    const int o = blockIdx.x;
    const int xcd = o & 7;
    const int k = o >> 3;
    const int mblk = k & 31;
    const int nloc = k >> 5;
    const int nblk = xcd * 6 + nloc;
    const int m0 = mblk * 128;
    const int n0g = nblk * 128;
    const int mi = n0g >> 11;
    const int n0 = n0g & 2047;

    const unsigned short* W16 = mi == 0 ? Wqb : (mi == 1 ? Wkb : Wvb);
    const float* bias = mi == 0 ? bq : (mi == 1 ? bk : bv);

    const int tid = threadIdx.x;
    const int lane = tid & 63;
    const int w = tid >> 6;
    const int g = lane >> 4;
    const int c = lane & 15;
    const int wr = w >> 1, wc = w & 1;

    __shared__ unsigned short As[128 * 64];
    __shared__ unsigned short Bs[128 * 64];

    f32x4 acc[4][4];
    #pragma unroll
    for (int i = 0; i < 4; ++i)
        #pragma unroll
        for (int j = 0; j < 4; ++j)
            acc[i][j] = f32x4{0.f, 0.f, 0.f, 0.f};

    gemm_core64(xbf, W16, m0, n0, tid, w, g, c, wr, wc, As, Bs, acc);

    #pragma unroll
    for (int j = 0; j < 4; ++j) {
        const int n = n0 + wc * 64 + j * 16 + c;
        const float bn = bias[n];
        const int hh = n >> 7, d = n & 127;
        #pragma unroll
        for (int i = 0; i < 4; ++i) {
            float y4[4];
            #pragma unroll
            for (int tq = 0; tq < 4; ++tq) y4[tq] = acc[i][j][tq] + bn;
            const int mb = m0 + wr * 64 + i * 16 + g * 4;
            if (mi == 0) {
                #pragma unroll
                for (int tq = 0; tq < 4; ++tq) {
                    int m = mb + tq; int b = m >> 10, s = m & 1023;
                    Qbf[((((size_t)b * 16 + hh) << 10) + s) * 128 + d] = f2bf(y4[tq] * QSCALE);
                }
            } else if (mi == 1) {
                #pragma unroll
                for (int tq = 0; tq < 4; ++tq) {
                    int m = mb + tq; int b = m >> 10, s = m & 1023;
                    kout[(((size_t)b * 16 + hh) * 2048 + 1024 + s) * 128 + d] = y4[tq];
                    Kbf[(((size_t)b * 16 + hh) << 18) + (size_t)(1024 + s) * 128 + d] = f2bf(y4[tq]);
                }
            } else {
                #pragma unroll
                for (int tq = 0; tq < 4; ++tq) {
                    int m = mb + tq; int b = m >> 10, s = m & 1023;
                    vout[(((size_t)b * 16 + hh) * 2048 + 1024 + s) * 128 + d] = y4[tq];
                }
                // Vtp baked image: new rows kv=1024+s -> tile 16+(s>>6), slot vperm(s&63)
                int b = mb >> 10, s = mb & 1023;
                const int t = 16 + (s >> 6);
                const int idx = d * 64 + (vperm4(s & 63) ^ ((d & 7) << 3));
                ushort4 pk = { f2bf(y4[0]), f2bf(y4[1]), f2bf(y4[2]), f2bf(y4[3]) };
                *(ushort4*)(Vtp + ((size_t)(b * 16 + hh) * 32 + t) * 8192 + idx) = pk;
            }
        }
    }
}

// Output projection GEMM: 512 linear blocks, XCD-chunked.
__global__ __launch_bounds__(256) void gemm_wo(
    const unsigned short* __restrict__ ctx, const unsigned short* __restrict__ Wob,
    const float* __restrict__ bo, float* __restrict__ outp)
{
    const int o = blockIdx.x;
    const int xcd = o & 7;
    const int k = o >> 3;
    const int mblk = k & 31;
    const int nloc = k >> 5;
    const int nblk = xcd * 2 + nloc;
    const int m0 = mblk * 128;
    const int n0 = nblk * 128;

    const int tid = threadIdx.x;
    const int lane = tid & 63;
    const int w = tid >> 6;
    const int g = lane >> 4;
    const int c = lane & 15;
    const int wr = w >> 1, wc = w & 1;

    __shared__ unsigned short As[128 * 64];
    __shared__ unsigned short Bs[128 * 64];

    f32x4 acc[4][4];
    #pragma unroll
    for (int i = 0; i < 4; ++i)
        #pragma unroll
        for (int j = 0; j < 4; ++j)
            acc[i][j] = f32x4{0.f, 0.f, 0.f, 0.f};

    gemm_core64(ctx, Wob, m0, n0, tid, w, g, c, wr, wc, As, Bs, acc);

    #pragma unroll
    for (int j = 0; j < 4; ++j) {
        const int n = n0 + wc * 64 + j * 16 + c;
        const float bn = bo[n];
        #pragma unroll
        for (int i = 0; i < 4; ++i) {
            const int mb = m0 + wr * 64 + i * 16 + g * 4;
            #pragma unroll
            for (int tq = 0; tq < 4; ++tq)
                outp[(size_t)(mb + tq) * 2048 + n] = acc[i][j][tq] + bn;
        }
    }
}

// ================= flash attention v9: 8 waves x 16 q-rows, all-DMA staging ==========
// (known-good: ~110us, 16 waves/CU)
__global__ __launch_bounds__(512) void attn9(
    const unsigned short* __restrict__ Qbf,   // [B,H,1024,128] pre-scaled
    const unsigned short* __restrict__ Kbf,   // [B,H,2048,128]
    const unsigned short* __restrict__ Vtp,   // [B,H,32,8192] baked LDS images
    unsigned short* __restrict__ Pp,          // [2][64][1024][128] bf16 partials
    float* __restrict__ Mp,                   // [2][64][1024]
    float* __restrict__ Lp)                   // [2][64][1024]
{
    const int o = blockIdx.x;
    const int xcd = o & 7;
    const int kk0 = o >> 3;
    const int half = kk0 & 1;
    const int qt = 7 - ((kk0 >> 1) & 7);      // heavy-first
    const int bh = (kk0 >> 4) * 8 + xcd;

    const int tid = threadIdx.x;              // 0..511
    const int lane = tid & 63;
    const int w = tid >> 6;                   // 0..7
    const int g = lane >> 4;
    const int c = lane & 15;
    const int cswz = (c & 7) << 3;

    __shared__ unsigned short Ks[2][64 * 128];   // 32 KB
    __shared__ unsigned short Vs[2][64 * 128];   // 32 KB ([d][p] image)

    const unsigned short* Qb = Qbf + ((size_t)bh * 1024 + qt * 128) * 128;
    const unsigned short* Kb = Kbf + ((size_t)bh << 18);
    const unsigned short* Vtile = Vtp + (size_t)bh * 32 * 8192;

    bf16x8 aq[4];
    #pragma unroll
    for (int kd = 0; kd < 4; ++kd)
        aq[kd] = *(const bf16x8*)(Qb + (w * 16 + c) * 128 + kd * 32 + g * 8);

    f32x4 od[8];
    #pragma unroll
    for (int nf = 0; nf < 8; ++nf)
        od[nf] = f32x4{0.f, 0.f, 0.f, 0.f};
    float mrow = -1e30f, lrow = 0.f;

    const int krow = tid >> 4;
    const int kswz = (((tid & 15) << 4) ^ ((krow & 7) << 4)) >> 1;
    const unsigned short* Kl = Kb + (size_t)krow * 128 + kswz;

    const int cnt = 9 + qt;
    const int t0 = half * cnt;
    const int limw = 1024 + qt * 128 + w * 16;

    {
        const int kv0 = t0 * 64;
        lds_load16(&Ks[0][w * 512], Kl + (size_t)kv0 * 128);
        lds_load16(&Ks[0][4096 + w * 512], Kl + (size_t)(kv0 + 32) * 128);
        const unsigned short* Vsrc = Vtile + (size_t)t0 * 8192 + tid * 8;
        lds_load16(&Vs[0][w * 512], Vsrc);
        lds_load16(&Vs[0][4096 + w * 512], Vsrc + 4096);
        __syncthreads();
    }

    int cur = 0;
    for (int t = t0; t < t0 + cnt; ++t) {
        const int kv0 = t * 64;
        const bool next = (t + 1 < t0 + cnt);

        if (next) {
            const int kvn = kv0 + 64;
            lds_load16(&Ks[cur ^ 1][w * 512], Kl + (size_t)kvn * 128);
            lds_load16(&Ks[cur ^ 1][4096 + w * 512], Kl + (size_t)(kvn + 32) * 128);
            const unsigned short* Vsrc = Vtile + (size_t)(t + 1) * 8192 + tid * 8;
            lds_load16(&Vs[cur ^ 1][w * 512], Vsrc);
            lds_load16(&Vs[cur ^ 1][4096 + w * 512], Vsrc + 4096);
        }

        const unsigned short* Ksc = &Ks[cur][0];
        const unsigned short* Vsc = &Vs[cur][0];

        f32x4 sc[4];
        #pragma unroll
        for (int n = 0; n < 4; ++n)
            sc[n] = f32x4{0.f, 0.f, 0.f, 0.f};
        #pragma unroll
        for (int kd = 0; kd < 4; ++kd) {
            bf16x8 bk[4];
            #pragma unroll
            for (int n = 0; n < 4; ++n)
                bk[n] = *(const bf16x8*)(&Ksc[(n * 16 + c) * 128 + ((kd * 32 + g * 8) ^ cswz)]);
            #pragma unroll
            for (int n = 0; n < 4; ++n)
                sc[n] = __builtin_amdgcn_mfma_f32_16x16x32_bf16(bk[n], aq[kd], sc[n], 0, 0, 0);
        }

        const bool need_mask = (kv0 + 63 > limw);
        if (need_mask) {
            const int lim = limw + c;
            #pragma unroll
            for (int n = 0; n < 4; ++n)
                #pragma unroll
                for (int j = 0; j < 4; ++j)
                    if (kv0 + n * 16 + g * 4 + j > lim) sc[n][j] = -1e30f;
        }
        {
            float t4[4];
            #pragma unroll
            for (int n = 0; n < 4; ++n)
                t4[n] = fmaxf(fmaxf(sc[n][0], sc[n][1]), fmaxf(sc[n][2], sc[n][3]));
            float rmax = fmaxf(fmaxf(t4[0], t4[1]), fmaxf(t4[2], t4[3]));
            rmax = fmaxf(rmax, __shfl_xor(rmax, 16));
            rmax = fmaxf(rmax, __shfl_xor(rmax, 32));

            if (!__all(rmax <= mrow + 8.0f)) {
                const float mnew = fmaxf(mrow, rmax);
                const float fs = exp2f(mrow - mnew);
                mrow = mnew;
                lrow *= fs;
                #pragma unroll
                for (int j = 0; j < 4; ++j) {
                    const float fsj = __shfl(fs, (lane & 48) | (g * 4 + j));
                    #pragma unroll
                    for (int nf = 0; nf < 8; ++nf)
                        od[nf][j] *= fsj;
                }
            }
            const float mm = mrow;
            float s4[4];
            #pragma unroll
            for (int n = 0; n < 4; ++n) {
                #pragma unroll
                for (int j = 0; j < 4; ++j)
                    sc[n][j] = exp2f(sc[n][j] - mm);
                s4[n] = (sc[n][0] + sc[n][1]) + (sc[n][2] + sc[n][3]);
            }
            float rsum = (s4[0] + s4[1]) + (s4[2] + s4[3]);
            rsum += __shfl_xor(rsum, 16);
            rsum += __shfl_xor(rsum, 32);
            lrow += rsum;
        }

        bf16x8 pa[2];
        #pragma unroll
        for (int kk = 0; kk < 2; ++kk)
            #pragma unroll
            for (int e = 0; e < 8; ++e)
                pa[kk][e] = (__bf16)sc[2 * kk + (e >> 2)][e & 3];

        #pragma unroll
        for (int kk = 0; kk < 2; ++kk) {
            #pragma unroll
            for (int nf = 0; nf < 8; ++nf) {
                bf16x8 bv = *(const bf16x8*)(&Vsc[(nf * 16 + c) * 64 + ((kk * 32 + g * 8) ^ cswz)]);
                od[nf] = __builtin_amdgcn_mfma_f32_16x16x32_bf16(pa[kk], bv, od[nf], 0, 0, 0);
            }
        }

        __syncthreads();
        cur ^= 1;
    }

    const size_t pbase = ((size_t)(half * 64 + bh) * 1024 + qt * 128) * 128;
    const int mlbase = (half * 64 + bh) * 1024 + qt * 128;
    if (lane < 16) {
        Mp[mlbase + w * 16 + c] = mrow;
        Lp[mlbase + w * 16 + c] = lrow;
    }
    #pragma unroll
    for (int j = 0; j < 4; ++j) {
        const float lj = __shfl(lrow, (lane & 48) | (g * 4 + j));
        const float rl = 1.0f / lj;
        const int ql = w * 16 + g * 4 + j;
        #pragma unroll
        for (int nf = 0; nf < 8; ++nf)
            Pp[pbase + (size_t)ql * 128 + nf * 16 + c] = f2bf(od[nf][j] * rl);
    }
}

// merge the two KV-split partials -> ctx bf16
__global__ __launch_bounds__(256) void merge_ctx(
    const unsigned short* __restrict__ Pp, const float* __restrict__ Mp,
    const float* __restrict__ Lp, unsigned short* __restrict__ ctx)
{
    const int idx = blockIdx.x * 256 + threadIdx.x;
    const int r = idx >> 4;
    const int dc = (idx & 15) << 3;
    const float m0 = Mp[r], m1 = Mp[65536 + r];
    const float l0 = Lp[r], l1 = Lp[65536 + r];
    const float M = fmaxf(m0, m1);
    float w0 = l0 * exp2f(m0 - M);
    float w1 = l1 * exp2f(m1 - M);
    const float inv = 1.0f / (w0 + w1);
    w0 *= inv; w1 *= inv;
    u16x8 a = *(const u16x8*)(Pp + (size_t)r * 128 + dc);
    u16x8 bb = *(const u16x8*)(Pp + (size_t)8388608 + (size_t)r * 128 + dc);
    const int bh = r >> 10, q = r & 1023;
    unsigned short* dst = ctx + ((size_t)(bh >> 4) * 1024 + q) * 2048 + (bh & 15) * 128 + dc;
    u16x8 outv;
    #pragma unroll
    for (int e = 0; e < 8; ++e)
        outv[e] = f2bf(w0 * bf2f(a[e]) + w1 * bf2f(bb[e]));
    *(u16x8*)dst = outv;
}

// ================= small-ws fallback =================
__global__ __launch_bounds__(256) void copy_cache(
    const float* __restrict__ kc, const float* __restrict__ vc,
    float* __restrict__ kout, float* __restrict__ vout)
{
    size_t i4 = (size_t)blockIdx.x * 256 + threadIdx.x;
    const float* src = blockIdx.y ? vc : kc;
    float* dst = blockIdx.y ? vout : kout;
    size_t e = i4 * 4;
    size_t bh = e >> 17, rem = e & 131071;
    f32x4 v = *(const f32x4*)(src + e);
    *(f32x4*)(dst + (bh << 18) + rem) = v;
}

template<int MODE, bool ABF16>
__global__ __launch_bounds__(256) void gemm_bt(
    const void* __restrict__ Ag, const float* __restrict__ Wf,
    const float* __restrict__ bias, void* __restrict__ dst)
{
    const int tid = threadIdx.x;
    const int lane = tid & 63;
    const int w = tid >> 6;
    const int g = lane >> 4;
    const int c = lane & 15;
    const int wr = w >> 1, wc = w & 1;
    const int m0 = blockIdx.y * 128;
    const int n0 = blockIdx.x * 128;

    __shared__ unsigned short As[128 * 40];
    __shared__ unsigned short Bs[128 * 40];

    f32x4 acc[4][4];
    #pragma unroll
    for (int i = 0; i < 4; ++i)
        #pragma unroll
        for (int j = 0; j < 4; ++j)
            acc[i][j] = f32x4{0.f, 0.f, 0.f, 0.f};

    for (int k0 = 0; k0 < DIMK; k0 += 32) {
        __syncthreads();
        if constexpr (ABF16) {
            const unsigned short* A16 = (const unsigned short*)Ag;
            #pragma unroll
            for (int r = 0; r < 2; ++r) {
                int e8 = r * 256 + tid;
                int row = e8 >> 2, col = (e8 & 3) << 3;
                *(uint4*)(&As[row * 40 + col]) =
                    *(const uint4*)(A16 + (size_t)(m0 + row) * DIMK + k0 + col);
            }
        } else {
            const float* Af = (const float*)Ag;
            #pragma unroll
            for (int r = 0; r < 4; ++r) {
                int e4 = r * 256 + tid;
                int row = e4 >> 3, col = (e4 & 7) << 2;
                f32x4 v = *(const f32x4*)(Af + (size_t)(m0 + row) * DIMK + k0 + col);
                ushort4 pk = { f2bf(v[0]), f2bf(v[1]), f2bf(v[2]), f2bf(v[3]) };
                *(ushort4*)(&As[row * 40 + col]) = pk;
            }
        }
        {
            #pragma unroll
            for (int r = 0; r < 4; ++r) {
                int e4 = r * 256 + tid;
                int row = e4 >> 3, col = (e4 & 7) << 2;
                f32x4 v = *(const f32x4*)(Wf + (size_t)(n0 + row) * DIMK + k0 + col);
                ushort4 pk = { f2bf(v[0]), f2bf(v[1]), f2bf(v[2]), f2bf(v[3]) };
                *(ushort4*)(&Bs[row * 40 + col]) = pk;
            }
        }
        __syncthreads();

        bf16x8 af[4], bfr[4];
        #pragma unroll
        for (int i = 0; i < 4; ++i)
            af[i] = *(const bf16x8*)(&As[(wr * 64 + i * 16 + c) * 40 + g * 8]);
        #pragma unroll
        for (int i = 0; i < 4; ++i)
            bfr[i] = *(const bf16x8*)(&Bs[(wc * 64 + i * 16 + c) * 40 + g * 8]);
        #pragma unroll
        for (int i = 0; i < 4; ++i)
            #pragma unroll
            for (int j = 0; j < 4; ++j)
                acc[i][j] = __builtin_amdgcn_mfma_f32_16x16x32_bf16(af[i], bfr[j], acc[i][j], 0, 0, 0);
    }

    #pragma unroll
    for (int j = 0; j < 4; ++j) {
        const int n = n0 + wc * 64 + j * 16 + c;
        const float bn = bias[n];
        #pragma unroll
        for (int i = 0; i < 4; ++i) {
            float y4[4];
            #pragma unroll
            for (int tq = 0; tq < 4; ++tq) y4[tq] = acc[i][j][tq] + bn;
            const int mb = m0 + wr * 64 + i * 16 + g * 4;
            if constexpr (MODE == 0) {
                #pragma unroll
                for (int tq = 0; tq < 4; ++tq) {
                    int m = mb + tq; int b = m >> 10, s = m & 1023;
                    int hh = n >> 7, d = n & 127;
                    ((unsigned short*)dst)[((((size_t)b * 16 + hh) << 10) + s) * 128 + d] = f2bf(y4[tq] * QSCALE);
                }
            } else if constexpr (MODE == 1) {
                #pragma unroll
                for (int tq = 0; tq < 4; ++tq) {
                    int m = mb + tq; int b = m >> 10, s = m & 1023;
                    int hh = n >> 7, d = n & 127;
                    ((float*)dst)[(((size_t)b * 16 + hh) * 2048 + 1024 + s) * 128 + d] = y4[tq];
                }
            } else {
                #pragma unroll
                for (int tq = 0; tq < 4; ++tq)
                    ((float*)dst)[(size_t)(mb + tq) * 2048 + n] = y4[tq];
            }
        }
    }
}

__global__ __launch_bounds__(256) void attn_stage(
    const unsigned short* __restrict__ Qbf,
    const float* __restrict__ Kf, const float* __restrict__ Vf,
    unsigned short* __restrict__ ctx)
{
    const int qt = blockIdx.x;
    const int bh = blockIdx.y;
    const int b = bh >> 4, h = bh & 15;
    const int tid = threadIdx.x;
    const int lane = tid & 63;
    const int w = tid >> 6;
    const int g = lane >> 4;
    const int c = lane & 15;

    __shared__ unsigned short Ksl[64 * 136];
    __shared__ unsigned short Vtl[128 * 72];
    __shared__ unsigned short Ps[4 * 32 * 72];

    bf16x8 aq[2][4];
    const unsigned short* Qb = Qbf + ((size_t)bh * 1024 + qt * 128) * 128;
    #pragma unroll
    for (int m2 = 0; m2 < 2; ++m2)
        #pragma unroll
        for (int kk = 0; kk < 4; ++kk)
            aq[m2][kk] = *(const bf16x8*)(Qb + (w * 32 + m2 * 16 + c) * 128 + kk * 32 + g * 8);

    f32x4 od[2][8];
    #pragma unroll
    for (int m2 = 0; m2 < 2; ++m2)
        #pragma unroll
        for (int nf = 0; nf < 8; ++nf)
            od[m2][nf] = f32x4{0.f, 0.f, 0.f, 0.f};
    float mrow[2][4], lrow[2][4];
    #pragma unroll
    for (int m2 = 0; m2 < 2; ++m2)
        #pragma unroll
        for (int j = 0; j < 4; ++j) { mrow[m2][j] = -1e30f; lrow[m2][j] = 0.f; }

    const float* Kb = Kf + (size_t)bh * 2048 * 128;
    const float* Vb = Vf + (size_t)bh * 2048 * 128;
    const int ntiles = 18 + 2 * qt;

    for (int t = 0; t < ntiles; ++t) {
        __syncthreads();
        const float* Kt = Kb + (size_t)t * 64 * 128;
        #pragma unroll
        for (int r = 0; r < 8; ++r) {
            int e4 = r * 256 + tid;
            int kv = e4 >> 5, d0 = (e4 & 31) << 2;
            f32x4 v = *(const f32x4*)(Kt + kv * 128 + d0);
            ushort4 pk = { f2bf(v[0]), f2bf(v[1]), f2bf(v[2]), f2bf(v[3]) };
            *(ushort4*)(&Ksl[kv * 136 + d0]) = pk;
        }
        const float* Vg = Vb + (size_t)t * 64 * 128;
        #pragma unroll
        for (int r = 0; r < 8; ++r) {
            int e4 = tid * 8 + r;
            int kv = e4 >> 5, d0 = (e4 & 31) << 2;
            f32x4 v = *(const f32x4*)(Vg + kv * 128 + d0);
            #pragma unroll
            for (int i = 0; i < 4; ++i)
                Vtl[(d0 + i) * 72 + kv] = f2bf(v[i]);
        }
        __syncthreads();

        f32x4 sc[2][4];
        #pragma unroll
        for (int m2 = 0; m2 < 2; ++m2)
            #pragma unroll
            for (int n = 0; n < 4; ++n)
                sc[m2][n] = f32x4{0.f, 0.f, 0.f, 0.f};
        #pragma unroll
        for (int kk = 0; kk < 4; ++kk) {
            bf16x8 bk[4];
            #pragma unroll
            for (int n = 0; n < 4; ++n)
                bk[n] = *(const bf16x8*)(&Ksl[(n * 16 + c) * 136 + kk * 32 + g * 8]);
            #pragma unroll
            for (int m2 = 0; m2 < 2; ++m2)
                #pragma unroll
                for (int n = 0; n < 4; ++n)
                    sc[m2][n] = __builtin_amdgcn_mfma_f32_16x16x32_bf16(aq[m2][kk], bk[n], sc[m2][n], 0, 0, 0);
        }

        const int kvbase = t * 64;
        #pragma unroll
        for (int m2 = 0; m2 < 2; ++m2) {
            #pragma unroll
            for (int j = 0; j < 4; ++j) {
                const int qg = qt * 128 + w * 32 + m2 * 16 + g * 4 + j;
                const int lim = qg + 1024;
                float rmax = -1e30f;
                #pragma unroll
                for (int n = 0; n < 4; ++n) {
                    float s = sc[m2][n][j] * QSCALE;
                    if (kvbase + n * 16 + c > lim) s = -1e30f;
                    sc[m2][n][j] = s;
                    rmax = fmaxf(rmax, s);
                }
                #pragma unroll
                for (int off = 1; off < 16; off <<= 1)
                    rmax = fmaxf(rmax, __shfl_xor(rmax, off));
                float mold = mrow[m2][j];
                float mnew = fmaxf(mold, rmax);
                mrow[m2][j] = mnew;
                float fs = exp2f(mold - mnew);
                float rsum = 0.f;
                #pragma unroll
                for (int n = 0; n < 4; ++n) {
                    float p = exp2f(sc[m2][n][j] - mnew);
                    sc[m2][n][j] = p;
                    rsum += p;
                }
                #pragma unroll
                for (int off = 1; off < 16; off <<= 1)
                    rsum += __shfl_xor(rsum, off);
                lrow[m2][j] = lrow[m2][j] * fs + rsum;
                #pragma unroll
                for (int nf = 0; nf < 8; ++nf)
                    od[m2][nf][j] *= fs;
            }
        }

        unsigned short* Pw = &Ps[w * 32 * 72];
        #pragma unroll
        for (int m2 = 0; m2 < 2; ++m2)
            #pragma unroll
            for (int n = 0; n < 4; ++n)
                #pragma unroll
                for (int j = 0; j < 4; ++j)
                    Pw[(m2 * 16 + g * 4 + j) * 72 + n * 16 + c] = f2bf(sc[m2][n][j]);

        #pragma unroll
        for (int kk = 0; kk < 2; ++kk) {
            bf16x8 ap0 = *(const bf16x8*)(&Ps[(w * 32 + c) * 72 + kk * 32 + g * 8]);
            bf16x8 ap1 = *(const bf16x8*)(&Ps[(w * 32 + 16 + c) * 72 + kk * 32 + g * 8]);
            #pragma unroll
            for (int nf = 0; nf < 8; ++nf) {
                bf16x8 bv = *(const bf16x8*)(&Vtl[(nf * 16 + c) * 72 + kk * 32 + g * 8]);
                od[0][nf] = __builtin_amdgcn_mfma_f32_16x16x32_bf16(ap0, bv, od[0][nf], 0, 0, 0);
                od[1][nf] = __builtin_amdgcn_mfma_f32_16x16x32_bf16(ap1, bv, od[1][nf], 0, 0, 0);
            }
        }
    }

    #pragma unroll
    for (int m2 = 0; m2 < 2; ++m2) {
        #pragma unroll
        for (int j = 0; j < 4; ++j) {
            const int qg = qt * 128 + w * 32 + m2 * 16 + g * 4 + j;
            const float rl = 1.0f / lrow[m2][j];
            #pragma unroll
            for (int nf = 0; nf < 8; ++nf) {
                const int d = nf * 16 + c;
                ctx[((size_t)b * 1024 + qg) * 2048 + h * 128 + d] = f2bf(od[m2][nf][j] * rl);
            }
        }
    }
}

extern "C" void kernel_launch(void* const* d_in, const int* in_sizes, int n_in,
                              void* d_out, int out_size, void* d_ws, size_t ws_size,
                              hipStream_t stream) {
    const float* x  = (const float*)d_in[0];
    const float* kc = (const float*)d_in[1];
    const float* vc = (const float*)d_in[2];
    const float* Wq = (const float*)d_in[3];
    const float* bq = (const float*)d_in[4];
    const float* Wk = (const float*)d_in[5];
    const float* bk = (const float*)d_in[6];
    const float* Wv = (const float*)d_in[7];
    const float* bv = (const float*)d_in[8];
    const float* Wo = (const float*)d_in[9];
    const float* bo = (const float*)d_in[10];

    float* outp = (float*)d_out;
    float* kout = outp + (size_t)8388608;
    float* vout = outp + (size_t)25165824;

    unsigned short* Qbf = (unsigned short*)d_ws;          //  8,388,608
    unsigned short* ctx = Qbf + (size_t)8388608;          //  8,388,608
    unsigned short* Kbf = ctx + (size_t)8388608;          // 16,777,216
    unsigned short* Vtp = Kbf + (size_t)16777216;         // 16,777,216 (baked V images)
    unsigned short* xbf = Vtp + (size_t)16777216;         //  8,388,608
    unsigned short* Wqb = xbf + (size_t)8388608;
    unsigned short* Wkb = Wqb + (size_t)4194304;
    unsigned short* Wvb = Wkb + (size_t)4194304;
    unsigned short* Wob = Wvb + (size_t)4194304;
    unsigned short* Pp = xbf;                             // reuse xbf+Wqb+Wkb
    float* Mp = (float*)Wvb;
    float* Lp = Mp + (size_t)131072;

    const bool full = ws_size >= (size_t)150994944;

    if (full) {
        prep_all<<<33792, 256, 0, stream>>>(x, Wq, Wk, Wv, Wo, kc, vc,
                                            xbf, Wqb, Wkb, Wvb, Wob,
                                            kout, Kbf, vout, Vtp);
        gemm_qkv<<<1536, 256, 0, stream>>>(xbf, Wqb, Wkb, Wvb, bq, bk, bv,
                                           Qbf, kout, Kbf, vout, Vtp);
        attn9<<<1024, 512, 0, stream>>>(Qbf, Kbf, Vtp, Pp, Mp, Lp);
        merge_ctx<<<4096, 256, 0, stream>>>(Pp, Mp, Lp, ctx);
        gemm_wo<<<512, 256, 0, stream>>>(ctx, Wob, bo, outp);
    } else {
        copy_cache<<<dim3(8192, 2), 256, 0, stream>>>(kc, vc, kout, vout);
        gemm_bt<0, false><<<dim3(16, 32), 256, 0, stream>>>(x, Wq, bq, Qbf);
        gemm_bt<1, false><<<dim3(16, 32), 256, 0, stream>>>(x, Wk, bk, kout);
        gemm_bt<1, false><<<dim3(16, 32), 256, 0, stream>>>(x, Wv, bv, vout);
        attn_stage<<<dim3(8, 64), 256, 0, stream>>>(Qbf, kout, vout, ctx);
        gemm_bt<2, true><<<dim3(16, 32), 256, 0, stream>>>(ctx, Wo, bo, outp);
    }
}